// Round 10
// baseline (275.466 us; speedup 1.0000x reference)
//
#include <hip/hip_runtime.h>
#include <hip/hip_fp16.h>
#include <math.h>

#define NNODES 100000
#define NT0 60000
#define NT1 40000
#define FD0 128
#define FD1 64
#define HID 64
#define HEADS 8
#define OUTD 16
#define AVEC 128
#define NE 250000
#define NG 8192
#define NB 8192

typedef _Float16 half8v __attribute__((ext_vector_type(8)));
typedef float f32x4 __attribute__((ext_vector_type(4)));

// workspace layout (float offsets)
#define OFF_TF16    0ull          // 3,200,000
#define OFF_FINALS  3200000ull    // 512
#define OFF_ACC     3200512ull    // 256
#define OFF_BETA    3200768ull    // 256
#define OFF_WC0     3201024ull    // 7,168  (f16 [112][128])
#define OFF_WC1     3208192ull    // 3,584  (f16 [112][64])
#define OFF_BC0     3211776ull    // 128
#define OFF_BC1     3211904ull    // 128
#define OFF_FC1H    3212032ull    // 32,768 (f16 [128][512])
#define OFF_P       3244800ull    // 2,400,000 (f16 P[2][100000][24])
#define OFF_SORTED  5644800ull    // 2,000,000 (500,000 int4; byte off % 16 == 0)
#define OFF_COUNTS  7644800ull    // 16,384 ints
#define OFF_CNTT    7661184ull    // 16,384 ints
#define OFF_CURS    7677568ull    // 16,384 ints
#define OFF_OFFS    7693952ull    // 16,640 ints (16,385 used)
#define OFF_FT16    7710592ull    // 4,194,304 (f16 2*NG*512)
// total = 11,904,896 floats = 47.6 MB

// ---- wprep: finals, Wcat = [W; A@W] f16, bcat = [b; A@b], zero acc ----
__global__ __launch_bounds__(256) void k_wprep(const float* __restrict__ r_vec,
     const float* __restrict__ attn0, const float* __restrict__ attn1,
     const float* __restrict__ W0v, const float* __restrict__ b0v,
     const float* __restrict__ W1v, const float* __restrict__ b1v,
     float* __restrict__ finals, __half* __restrict__ wc0, float* __restrict__ bc0,
     __half* __restrict__ wc1, float* __restrict__ bc1,
     float* __restrict__ acc, float* __restrict__ beta){
  __shared__ float2 fl[192];      // [pi][pair]
  __shared__ float Ash[48][66];   // A[cg][d]
  int t = threadIdx.x;
  if (t < 32){
    int j = t;
    const float2* rv = (const float2*)r_vec;
    float2 r0 = rv[j];
    float2 r1 = rv[32 + j];
    float n0 = rsqrtf(r0.x*r0.x + r0.y*r0.y);
    float n1 = rsqrtf(r1.x*r1.x + r1.y*r1.y);
    r0.x *= n0; r0.y *= n0; r1.x *= n1; r1.y *= n1;
    float2 rf1 = make_float2(r0.x, -r0.y);   // conj(r0)
    float2 rf3 = make_float2(r1.x, -r1.y);   // conj(r1)
    float2 F00 = make_float2(rf1.x*r0.x - rf1.y*r0.y, rf1.x*r0.y + rf1.y*r0.x);
    float2 F10 = make_float2(rf3.x*r1.x - rf3.y*r1.y, rf3.x*r1.y + rf3.y*r1.x);
    float2 one = make_float2(1.f, 0.f);
    float2* F = (float2*)finals;
    F[0*32+j] = F00; F[1*32+j] = rf1; F[2*32+j] = one;
    F[3*32+j] = F10; F[4*32+j] = rf3; F[5*32+j] = one;
    fl[0*32+j] = F00; fl[1*32+j] = rf1; fl[2*32+j] = one;
    fl[3*32+j] = F10; fl[4*32+j] = rf3; fl[5*32+j] = one;
  }
  __syncthreads();
  for (int idx = t; idx < 1536; idx += 256){
    int pair = idx & 31, k = (idx >> 5) & 7, pi = idx >> 8;   // pi 0..5
    const float* at = (pi >= 3) ? attn1 : attn0;
    float2 f = fl[pi*32 + pair];
    float a0 = at[k*64 + 2*pair], a1 = at[k*64 + 2*pair + 1];
    Ash[pi*8+k][2*pair]     = (f.x*a0 + f.y*a1) * (1.f/3.f);
    Ash[pi*8+k][2*pair + 1] = (f.x*a1 - f.y*a0) * (1.f/3.f);
  }
  __syncthreads();
  // Wcat0: [112][128] f16
  for (int q = t; q < 112*128; q += 256){
    int c = q >> 7, f = q & 127;
    float v;
    if (c < 64) v = W0v[c*128 + f];
    else {
      float s = 0.f;
      #pragma unroll 8
      for (int d = 0; d < 64; ++d) s += Ash[c-64][d] * W0v[d*128 + f];
      v = s;
    }
    wc0[q] = __float2half(v);
  }
  // Wcat1: [112][64] f16
  for (int q = t; q < 112*64; q += 256){
    int c = q >> 6, f = q & 63;
    float v;
    if (c < 64) v = W1v[c*64 + f];
    else {
      float s = 0.f;
      #pragma unroll 8
      for (int d = 0; d < 64; ++d) s += Ash[c-64][d] * W1v[d*64 + f];
      v = s;
    }
    wc1[q] = __float2half(v);
  }
  if (t < 112){
    float s0, s1;
    if (t < 64){ s0 = b0v[t]; s1 = b1v[t]; }
    else {
      s0 = 0.f; s1 = 0.f;
      #pragma unroll 8
      for (int d = 0; d < 64; ++d){
        s0 += Ash[t-64][d] * b0v[d];
        s1 += Ash[t-64][d] * b1v[d];
      }
    }
    bc0[t] = s0; bc1[t] = s1;
  }
  acc[t] = 0.f;
  if (t < 2) beta[t] = 0.f;
}

// ---- fc1_w -> f16 ----
__global__ void k_cvtw(const float* __restrict__ fc1_w, __half* __restrict__ fc1h){
  int t = blockIdx.x*blockDim.x + threadIdx.x;
  fc1h[t] = __float2half(fc1_w[t]);
}

// ---- fused transform+P via MFMA: [tf16 | P] = feat @ Wcat.T + bcat ----
// per block: 64 nodes, 4 waves; per wave: 16 nodes x 112 cols (7 tiles of 16)
__global__ __launch_bounds__(256) void k_tform(const float* __restrict__ feat0,
      const int* __restrict__ idx0, const float* __restrict__ feat1,
      const int* __restrict__ idx1,
      const __half* __restrict__ wc0, const float* __restrict__ bc0,
      const __half* __restrict__ wc1, const float* __restrict__ bc1,
      __half* __restrict__ tf16, __half* __restrict__ P){
  const int nb0 = (NT0 + 63)/64;
  int bid = blockIdx.x;
  const float* feat; const int* idx; const __half* wc; const float* bc;
  int n_nodes, F, m0;
  if (bid < nb0){ feat=feat0; idx=idx0; wc=wc0; bc=bc0; n_nodes=NT0; F=FD0; m0=bid*64; }
  else { feat=feat1; idx=idx1; wc=wc1; bc=bc1; n_nodes=NT1; F=FD1; m0=(bid-nb0)*64; }
  __shared__ int idxs[64];
  int t = threadIdx.x;
  if (t < 64){
    int gm = m0 + t; if (gm > n_nodes - 1) gm = n_nodes - 1;
    idxs[t] = idx[gm];
  }
  __syncthreads();
  int w = t >> 6, l = t & 63;
  int lr = l & 15, lk = l >> 4;
  int gr = m0 + w*16 + lr; if (gr > n_nodes - 1) gr = n_nodes - 1;
  const float* arow = feat + (size_t)gr*F;

  f32x4 acc7[7];
  #pragma unroll
  for (int ct = 0; ct < 7; ++ct) acc7[ct] = (f32x4){0.f,0.f,0.f,0.f};

  int nk = F >> 5;
  for (int kk = 0; kk < nk; ++kk){
    int koff = kk*32 + lk*8;
    float4 ua = *(const float4*)(arow + koff);
    float4 ub = *(const float4*)(arow + koff + 4);
    half8v a = {(_Float16)ua.x,(_Float16)ua.y,(_Float16)ua.z,(_Float16)ua.w,
                (_Float16)ub.x,(_Float16)ub.y,(_Float16)ub.z,(_Float16)ub.w};
    #pragma unroll
    for (int ct = 0; ct < 7; ++ct){
      half8v b = *(const half8v*)(wc + (size_t)(ct*16 + lr)*F + koff);
      acc7[ct] = __builtin_amdgcn_mfma_f32_16x16x32_f16(a, b, acc7[ct], 0, 0, 0);
    }
  }

  // C/D layout: col = lane&15 (output dim), row = (lane>>4)*4 + reg (node)
  #pragma unroll
  for (int ct = 0; ct < 7; ++ct){
    int col = ct*16 + lr;
    float bv = bc[col];
    #pragma unroll
    for (int r = 0; r < 4; ++r){
      int nl = w*16 + lk*4 + r;
      int gm = m0 + nl;
      if (gm < n_nodes){
        __half hv = __float2half(acc7[ct][r] + bv);
        int gn = idxs[nl];
        if (col < 64) tf16[(size_t)gn*64 + col] = hv;
        else {
          int cg = col - 64;
          int p = cg >= 24;
          P[(size_t)p*2400000 + (size_t)gn*24 + (cg - p*24)] = hv;
        }
      }
    }
  }
}

// ---- zero int buffer ----
__global__ void k_zeroi(int* __restrict__ p, int n){
  int t = blockIdx.x*blockDim.x + threadIdx.x;
  if (t < n) p[t] = 0;
}

// ---- histograms: dst (both p) + tgt (both p) ----
__global__ void k_hist3(const int* __restrict__ d0, const int* __restrict__ d1,
                        const int* __restrict__ t0, const int* __restrict__ t1,
                        int* __restrict__ counts, int* __restrict__ cntt){
  int e = blockIdx.x*blockDim.x + threadIdx.x;
  if (e < NE) atomicAdd(&counts[d0[e]], 1);
  else if (e < 2*NE) atomicAdd(&counts[NG + d1[e-NE]], 1);
  else if (e < 2*NE + NB) atomicAdd(&cntt[t0[e-2*NE]], 1);
  else if (e < 2*NE + 2*NB) atomicAdd(&cntt[NG + t1[e-2*NE-NB]], 1);
}

// ---- exclusive scan over 16384 counts; also zero cursors ----
__global__ __launch_bounds__(1024) void k_scan(const int* __restrict__ counts,
                                               int* __restrict__ offs,
                                               int* __restrict__ curs){
  __shared__ int lds[1024];
  int t = threadIdx.x;
  int base = t*16;
  int v[16]; int sum = 0;
  #pragma unroll
  for (int i = 0; i < 16; ++i){ v[i] = counts[base+i]; sum += v[i]; }
  lds[t] = sum;
  __syncthreads();
  for (int off = 1; off < 1024; off <<= 1){
    int x = (t >= off) ? lds[t-off] : 0;
    __syncthreads();
    lds[t] += x;
    __syncthreads();
  }
  int excl = lds[t] - sum;
  #pragma unroll
  for (int i = 0; i < 16; ++i){ offs[base+i] = excl; excl += v[i]; curs[base+i] = 0; }
  if (t == 1023) offs[2*NG] = excl;
}

// ---- scatter both metapaths' edges into dst-sorted order ----
__global__ void k_scatter2(const int* __restrict__ m0, const int* __restrict__ d0,
                           const int* __restrict__ m1, const int* __restrict__ d1,
                           const int* __restrict__ offs, int* __restrict__ curs,
                           int4* __restrict__ sorted){
  int e = blockIdx.x*blockDim.x + threadIdx.x;
  if (e >= 2*NE) return;
  const int* mp; int d;
  if (e < NE){ mp = m0 + (size_t)e*3; d = d0[e]; }
  else { mp = m1 + (size_t)(e-NE)*3; d = NG + d1[e-NE]; }
  int pos = offs[d] + atomicAdd(&curs[d], 1);
  sorted[pos] = make_int4(mp[0], mp[1], mp[2], 0);
}

// ---- fused per-segment softmax-agg; stores elu(ft) f16; s in phase A ----
__global__ __launch_bounds__(64) void k_seg(const __half* __restrict__ tf16,
                                            const __half* __restrict__ P,
                                            const int4* __restrict__ sorted,
                                            const int* __restrict__ offs,
                                            const float* __restrict__ finals,
                                            __half* __restrict__ ft16o){
  int bid = blockIdx.x;
  int p = bid >> 13;
  int lane = threadIdx.x;
  int hw = lane >> 5, j = lane & 31;
  int start = offs[bid], end = offs[bid+1];
  __half2* ftw = (__half2*)(ft16o + (size_t)bid*512);
  if (start == end){
    #pragma unroll
    for (int kk = 0; kk < 4; ++kk) ftw[(hw*4+kk)*32 + j] = __floats2half2_rn(0.f, 0.f);
    return;
  }
  const float2* F2 = (const float2*)(finals + p*192);
  float2 f0 = F2[j], f1 = F2[32 + j];
  const __half2* tfh = (const __half2*)tf16;
  const __half* Pp = P + (size_t)p*2400000;

  __shared__ int4 ndb[64];
  __shared__ float wb[64][8];

  float sA[8], ur[8], ui[8];
  #pragma unroll
  for (int k = 0; k < 8; ++k){ sA[k] = 0.f; ur[k] = 0.f; ui[k] = 0.f; }

  for (int c = start; c < end; c += 64){
    int n = end - c; if (n > 64) n = 64;
    // ---- phase A: logits + s accumulation (lane-per-edge) ----
    if (lane < n){
      int4 nd = sorted[c + lane];
      ndb[lane] = nd;
      float4 rA = *(const float4*)(Pp + (size_t)nd.x*24);
      float4 rB = *(const float4*)(Pp + (size_t)nd.y*24 + 8);
      float4 rC = *(const float4*)(Pp + (size_t)nd.z*24 + 16);
      const __half2* ha = (const __half2*)&rA;
      const __half2* hb = (const __half2*)&rB;
      const __half2* hc = (const __half2*)&rC;
      float w[8];
      #pragma unroll
      for (int m = 0; m < 4; ++m){
        float2 va = __half22float2(ha[m]);
        float2 vb = __half22float2(hb[m]);
        float2 vc = __half22float2(hc[m]);
        float x0 = va.x + vb.x + vc.x;
        float x1 = va.y + vb.y + vc.y;
        x0 = x0 > 0.f ? x0 : 0.01f*x0;
        x1 = x1 > 0.f ? x1 : 0.01f*x1;
        w[2*m]   = __expf(x0);
        w[2*m+1] = __expf(x1);
      }
      #pragma unroll
      for (int k = 0; k < 8; ++k) sA[k] += w[k];
      *(float4*)&wb[lane][0] = make_float4(w[0], w[1], w[2], w[3]);
      *(float4*)&wb[lane][4] = make_float4(w[4], w[5], w[6], w[7]);
    }
    __syncthreads();
    // ---- phase B: weighted aggregation (half-wave per edge) ----
    int cend = c + n;
    for (int i = c + hw; i < cend; i += 2){
      int e = i - c;
      int4 nd = ndb[e];
      float4 wlo = *(const float4*)&wb[e][0];
      float4 whi = *(const float4*)&wb[e][4];
      float2 v0 = __half22float2(tfh[(size_t)nd.x*32 + j]);
      float2 v1 = __half22float2(tfh[(size_t)nd.y*32 + j]);
      float2 v2 = __half22float2(tfh[(size_t)nd.z*32 + j]);
      float hre = (v0.x*f0.x - v0.y*f0.y) + (v1.x*f1.x - v1.y*f1.y) + v2.x;
      float him = (v0.x*f0.y + v0.y*f0.x) + (v1.x*f1.y + v1.y*f1.x) + v2.y;
      ur[0] += wlo.x*hre; ui[0] += wlo.x*him;
      ur[1] += wlo.y*hre; ui[1] += wlo.y*him;
      ur[2] += wlo.z*hre; ui[2] += wlo.z*him;
      ur[3] += wlo.w*hre; ui[3] += wlo.w*him;
      ur[4] += whi.x*hre; ui[4] += whi.x*him;
      ur[5] += whi.y*hre; ui[5] += whi.y*him;
      ur[6] += whi.z*hre; ui[6] += whi.z*him;
      ur[7] += whi.w*hre; ui[7] += whi.w*him;
    }
    __syncthreads();
  }
  // merge half-wave u partials; full-wave reduce s
  #pragma unroll
  for (int k = 0; k < 8; ++k){
    ur[k] += __shfl_xor(ur[k], 32);
    ui[k] += __shfl_xor(ui[k], 32);
    float v = sA[k];
    #pragma unroll
    for (int mask = 1; mask < 64; mask <<= 1) v += __shfl_xor(v, mask);
    sA[k] = v;
  }
  #pragma unroll
  for (int kk = 0; kk < 4; ++kk){
    int k = hw*4 + kk;
    float inv = 1.f / (3.f * sA[k]);
    float re = ur[k]*inv, im = ui[k]*inv;
    re = re > 0.f ? re : expm1f(re);    // elu fused
    im = im > 0.f ? im : expm1f(im);
    ftw[k*32 + j] = __floats2half2_rn(re, im);
  }
}

// ---- s1 via MFMA (validated layout): no LDS, fragments from global ----
__global__ __launch_bounds__(256) void k_s1g(const __half* __restrict__ ft16o,
                                             const int* __restrict__ cntt,
                                             const __half* __restrict__ fc1h,
                                             const float* __restrict__ fc1_b,
                                             float* __restrict__ acc_p){
  int bid = blockIdx.x;
  int p  = bid >> 8;
  int rb = bid & 255;
  int t = threadIdx.x;
  int w = t >> 6, l = t & 63;
  int rowbase = rb*32 + (w & 1)*16;
  int colbase = (w >> 1)*64;
  int lr = l & 15, lk = l >> 4;

  const half8v* Ab = (const half8v*)(ft16o + ((size_t)p*NG + rowbase)*512);
  f32x4 acc[4] = {{0.f,0.f,0.f,0.f},{0.f,0.f,0.f,0.f},
                  {0.f,0.f,0.f,0.f},{0.f,0.f,0.f,0.f}};

  #pragma unroll 4
  for (int kk = 0; kk < 16; ++kk){
    half8v a = Ab[(size_t)lr*64 + kk*4 + lk];
    #pragma unroll
    for (int ct = 0; ct < 4; ++ct){
      const half8v* Bb = (const half8v*)(fc1h + (size_t)(colbase + ct*16 + lr)*512);
      half8v b = Bb[kk*4 + lk];
      acc[ct] = __builtin_amdgcn_mfma_f32_16x16x32_f16(a, b, acc[ct], 0, 0, 0);
    }
  }

  float cf[4];
  #pragma unroll
  for (int r = 0; r < 4; ++r)
    cf[r] = (float)cntt[p*NG + rowbase + lk*4 + r];
  #pragma unroll
  for (int ct = 0; ct < 4; ++ct){
    int col = colbase + ct*16 + lr;
    float bv = fc1_b[col];
    float sv = 0.f;
    #pragma unroll
    for (int r = 0; r < 4; ++r)
      sv += cf[r] * tanhf(acc[ct][r] + bv);
    sv += __shfl_xor(sv, 16);
    sv += __shfl_xor(sv, 32);
    if (l < 16) atomicAdd(&acc_p[p*128 + col], sv);
  }
}

// ---- beta softmax over 2 metapaths ----
__global__ void k_beta(const float* __restrict__ acc, const float* __restrict__ fc2_w,
                       float* __restrict__ beta){
  int t = threadIdx.x;  // 64
  float s0 = acc[t]*fc2_w[t] + acc[t+64]*fc2_w[t+64];
  float s1 = acc[128+t]*fc2_w[t] + acc[192+t]*fc2_w[t+64];
  #pragma unroll
  for (int mask = 1; mask < 64; mask <<= 1){
    s0 += __shfl_xor(s0, mask, 64);
    s1 += __shfl_xor(s1, mask, 64);
  }
  if (t == 0){
    float z0 = s0 / (float)NB, z1 = s1 / (float)NB;
    float mz = fmaxf(z0, z1);
    float e0 = expf(z0 - mz), e1 = expf(z1 - mz);
    float inv = 1.f / (e0 + e1);
    beta[0] = e0*inv; beta[1] = e1*inv;
  }
}

// ---- hagg + logits (ft already elu'd, f16) ----
__global__ void k_final(const __half* __restrict__ ft0, const __half* __restrict__ ft1,
                        const int* __restrict__ tgt0, const int* __restrict__ tgt1,
                        const float* __restrict__ beta, const float* __restrict__ fc_w,
                        const float* __restrict__ fc_b, float* __restrict__ d_out){
  __shared__ float lds[512];
  int b = blockIdx.x, t = threadIdx.x;  // 512 threads
  float b0 = beta[0], b1 = beta[1];
  int g0 = tgt0[b], g1 = tgt1[b];
  float v0 = __half2float(ft0[(size_t)g0*512 + t]);
  float v1 = __half2float(ft1[(size_t)g1*512 + t]);
  float h = b0*v0 + b1*v1;
  lds[t] = h;
  d_out[(size_t)NB*OUTD + (size_t)b*512 + t] = h;
  __syncthreads();
  int o = t >> 5, j = t & 31;
  float s = 0.f;
  const float* w = fc_w + o*512;
  for (int d = j; d < 512; d += 32) s += lds[d]*w[d];
  #pragma unroll
  for (int mask = 1; mask < 32; mask <<= 1) s += __shfl_xor(s, mask, 32);
  if (j == 0) d_out[(size_t)b*OUTD + o] = s + fc_b[o];
}

extern "C" void kernel_launch(void* const* d_in, const int* in_sizes, int n_in,
                              void* d_out, int out_size, void* d_ws, size_t ws_size,
                              hipStream_t stream){
  const float* feat0  = (const float*)d_in[0];
  const float* feat1  = (const float*)d_in[1];
  const float* W0     = (const float*)d_in[2];
  const float* b0     = (const float*)d_in[3];
  const float* W1     = (const float*)d_in[4];
  const float* b1     = (const float*)d_in[5];
  const float* r_vec  = (const float*)d_in[6];
  const float* attn0  = (const float*)d_in[7];
  const float* attn1  = (const float*)d_in[8];
  const float* fc1_w  = (const float*)d_in[9];
  const float* fc1_b  = (const float*)d_in[10];
  const float* fc2_w  = (const float*)d_in[11];
  const float* fc_w   = (const float*)d_in[12];
  const float* fc_b   = (const float*)d_in[13];
  const int*   idx0   = (const int*)d_in[14];
  const int*   idx1   = (const int*)d_in[15];
  const int*   mpi0   = (const int*)d_in[16];
  const int*   mdst0  = (const int*)d_in[17];
  const int*   mtgt0  = (const int*)d_in[18];
  const int*   mpi1   = (const int*)d_in[19];
  const int*   mdst1  = (const int*)d_in[20];
  const int*   mtgt1  = (const int*)d_in[21];

  float* ws      = (float*)d_ws;
  __half* tf16   = (__half*)(ws + OFF_TF16);
  float* finals  = ws + OFF_FINALS;
  float* acc     = ws + OFF_ACC;
  float* beta    = ws + OFF_BETA;
  __half* wc0    = (__half*)(ws + OFF_WC0);
  __half* wc1    = (__half*)(ws + OFF_WC1);
  float* bc0     = ws + OFF_BC0;
  float* bc1     = ws + OFF_BC1;
  __half* fc1h   = (__half*)(ws + OFF_FC1H);
  __half* P      = (__half*)(ws + OFF_P);
  int4*  sorted  = (int4*)(ws + OFF_SORTED);
  int*   counts  = (int*)(ws + OFF_COUNTS);
  int*   cntt    = (int*)(ws + OFF_CNTT);
  int*   curs    = (int*)(ws + OFF_CURS);
  int*   offs    = (int*)(ws + OFF_OFFS);
  __half* ft16o  = (__half*)(ws + OFF_FT16);
  __half* ft0h   = ft16o;
  __half* ft1h   = ft16o + (size_t)NG*512;

  k_wprep<<<1, 256, 0, stream>>>(r_vec, attn0, attn1, W0, b0, W1, b1,
                                 finals, wc0, bc0, wc1, bc1, acc, beta);
  k_cvtw<<<256, 256, 0, stream>>>(fc1_w, fc1h);
  k_zeroi<<<128, 256, 0, stream>>>(counts, 4*NG);
  k_hist3<<<(2*NE + 2*NB + 255)/256, 256, 0, stream>>>(mdst0, mdst1, mtgt0, mtgt1,
                                                       counts, cntt);
  k_scan<<<1, 1024, 0, stream>>>(counts, offs, curs);
  k_scatter2<<<(2*NE + 255)/256, 256, 0, stream>>>(mpi0, mdst0, mpi1, mdst1,
                                                   offs, curs, sorted);

  k_tform<<<(NT0 + 63)/64 + (NT1 + 63)/64, 256, 0, stream>>>(
      feat0, idx0, feat1, idx1, wc0, bc0, wc1, bc1, tf16, P);

  k_seg<<<2*NG, 64, 0, stream>>>(tf16, P, sorted, offs, finals, ft16o);

  k_s1g<<<512, 256, 0, stream>>>(ft16o, cntt, fc1h, fc1_b, acc);
  k_beta<<<1, 64, 0, stream>>>(acc, fc2_w, beta);
  k_final<<<NB, 512, 0, stream>>>(ft0h, ft1h, mtgt0, mtgt1, beta, fc_w, fc_b,
                                  (float*)d_out);
}

// Round 11
// 230.392 us; speedup vs baseline: 1.1956x; 1.1956x over previous
//
#include <hip/hip_runtime.h>
#include <hip/hip_fp16.h>
#include <math.h>

#define NNODES 100000
#define NT0 60000
#define NT1 40000
#define FD0 128
#define FD1 64
#define HID 64
#define HEADS 8
#define OUTD 16
#define AVEC 128
#define NE 250000
#define NG 8192
#define NB 8192

typedef _Float16 half8v __attribute__((ext_vector_type(8)));
typedef float f32x4 __attribute__((ext_vector_type(4)));

// workspace layout (float offsets)
#define OFF_TF16    0ull          // 3,200,000
#define OFF_FINALS  3200000ull    // 512
#define OFF_ACC     3200512ull    // 256
#define OFF_BETA    3200768ull    // 256
#define OFF_WC0     3201024ull    // 7,168  (f16 [112][128])
#define OFF_WC1     3208192ull    // 3,584  (f16 [112][64])
#define OFF_BC0     3211776ull    // 128
#define OFF_BC1     3211904ull    // 128
#define OFF_FC1H    3212032ull    // 32,768 (f16 [128][512])
#define OFF_P       3244800ull    // 2,400,000 (f16 P[2][100000][24])
#define OFF_SORTED  5644800ull    // 2,000,000 (500,000 int4; byte off % 16 == 0)
#define OFF_COUNTS  7644800ull    // 16,384 ints
#define OFF_CNTT    7661184ull    // 16,384 ints
#define OFF_CURS    7677568ull    // 16,384 ints
#define OFF_OFFS    7693952ull    // 16,640 ints (16,385 used)
#define OFF_FT16    7710592ull    // 4,194,304 (f16 2*NG*512)
// total = 11,904,896 floats = 47.6 MB

// ---- compute one rotation float2 for (pi, pair j) from r_vec ----
__device__ __forceinline__ float2 rot_pair(const float* r_vec, int pi, int j){
  const float2* rv = (const float2*)r_vec;
  int rel = pi >= 3 ? 1 : 0;
  float2 r = rv[rel*32 + j];
  float n = rsqrtf(r.x*r.x + r.y*r.y);
  r.x *= n; r.y *= n;
  float2 rf = make_float2(r.x, -r.y);           // conj
  int pos = pi - rel*3;
  if (pos == 2) return make_float2(1.f, 0.f);
  if (pos == 1) return rf;
  return make_float2(rf.x*r.x - rf.y*r.y, rf.x*r.y + rf.y*r.x);  // rf * r
}

// ---- prep0: finals + zero acc/beta (1 block, 64 threads) ----
__global__ void k_prep0(const float* __restrict__ r_vec, float* __restrict__ finals,
                        float* __restrict__ acc, float* __restrict__ beta){
  int t = threadIdx.x;
  if (t < 32){
    float2* F = (float2*)finals;
    #pragma unroll
    for (int pi = 0; pi < 6; ++pi) F[pi*32 + t] = rot_pair(r_vec, pi, t);
  }
  for (int q = t; q < 256; q += 64) acc[q] = 0.f;
  if (t < 2) beta[t] = 0.f;
}

// ---- wcat: rows of Wcat0/Wcat1 (+bc) and fc1h conversion, fully parallel ----
// grid 288 x 128: blocks 0..111 -> wc0 rows, 112..223 -> wc1 rows, 224..287 -> fc1h
__global__ __launch_bounds__(128) void k_wcat(const float* __restrict__ r_vec,
     const float* __restrict__ attn0, const float* __restrict__ attn1,
     const float* __restrict__ W0v, const float* __restrict__ b0v,
     const float* __restrict__ W1v, const float* __restrict__ b1v,
     const float* __restrict__ fc1_w,
     __half* __restrict__ wc0, float* __restrict__ bc0,
     __half* __restrict__ wc1, float* __restrict__ bc1,
     __half* __restrict__ fc1h){
  int bid = blockIdx.x;
  int t = threadIdx.x;
  if (bid >= 224){
    int base = (bid - 224)*1024;
    for (int i = t; i < 1024; i += 128)
      fc1h[base + i] = __float2half(fc1_w[base + i]);
    return;
  }
  int type = bid >= 112;
  int c = bid - type*112;
  int F = type ? FD1 : FD0;
  const float* W  = type ? W1v : W0v;
  const float* bv = type ? b1v : b0v;
  __half* wc = type ? wc1 : wc0;
  float* bc  = type ? bc1 : bc0;

  if (c < 64){
    for (int f = t; f < F; f += 128) wc[(size_t)c*F + f] = __float2half(W[(size_t)c*F + f]);
    if (t == 0) bc[c] = bv[c];
    return;
  }
  // dot row: a = A[cg] (length 64), wc[c][f] = sum_d a[d]*W[d][f]
  __shared__ float a[64];
  int cg = c - 64;          // 0..47
  int pi = cg >> 3, k = cg & 7;
  if (t < 32){
    float2 f = rot_pair(r_vec, pi, t);
    const float* at = (pi >= 3) ? attn1 : attn0;
    float a0 = at[k*64 + 2*t], a1 = at[k*64 + 2*t + 1];
    a[2*t]     = (f.x*a0 + f.y*a1) * (1.f/3.f);
    a[2*t + 1] = (f.x*a1 - f.y*a0) * (1.f/3.f);
  }
  __syncthreads();
  for (int f = t; f < F; f += 128){
    float s = 0.f;
    #pragma unroll 16
    for (int d = 0; d < 64; ++d) s += a[d] * W[(size_t)d*F + f];
    wc[(size_t)c*F + f] = __float2half(s);
  }
  if (t == 0){
    float s = 0.f;
    #pragma unroll 16
    for (int d = 0; d < 64; ++d) s += a[d] * bv[d];
    bc[c] = s;
  }
}

// ---- fused transform+P via MFMA: [tf16 | P] = feat @ Wcat.T + bcat ----
__global__ __launch_bounds__(256) void k_tform(const float* __restrict__ feat0,
      const int* __restrict__ idx0, const float* __restrict__ feat1,
      const int* __restrict__ idx1,
      const __half* __restrict__ wc0, const float* __restrict__ bc0,
      const __half* __restrict__ wc1, const float* __restrict__ bc1,
      __half* __restrict__ tf16, __half* __restrict__ P){
  const int nb0 = (NT0 + 63)/64;
  int bid = blockIdx.x;
  const float* feat; const int* idx; const __half* wc; const float* bc;
  int n_nodes, F, m0;
  if (bid < nb0){ feat=feat0; idx=idx0; wc=wc0; bc=bc0; n_nodes=NT0; F=FD0; m0=bid*64; }
  else { feat=feat1; idx=idx1; wc=wc1; bc=bc1; n_nodes=NT1; F=FD1; m0=(bid-nb0)*64; }
  __shared__ int idxs[64];
  int t = threadIdx.x;
  if (t < 64){
    int gm = m0 + t; if (gm > n_nodes - 1) gm = n_nodes - 1;
    idxs[t] = idx[gm];
  }
  __syncthreads();
  int w = t >> 6, l = t & 63;
  int lr = l & 15, lk = l >> 4;
  int gr = m0 + w*16 + lr; if (gr > n_nodes - 1) gr = n_nodes - 1;
  const float* arow = feat + (size_t)gr*F;

  f32x4 acc7[7];
  #pragma unroll
  for (int ct = 0; ct < 7; ++ct) acc7[ct] = (f32x4){0.f,0.f,0.f,0.f};

  int nk = F >> 5;
  for (int kk = 0; kk < nk; ++kk){
    int koff = kk*32 + lk*8;
    float4 ua = *(const float4*)(arow + koff);
    float4 ub = *(const float4*)(arow + koff + 4);
    half8v a = {(_Float16)ua.x,(_Float16)ua.y,(_Float16)ua.z,(_Float16)ua.w,
                (_Float16)ub.x,(_Float16)ub.y,(_Float16)ub.z,(_Float16)ub.w};
    #pragma unroll
    for (int ct = 0; ct < 7; ++ct){
      half8v b = *(const half8v*)(wc + (size_t)(ct*16 + lr)*F + koff);
      acc7[ct] = __builtin_amdgcn_mfma_f32_16x16x32_f16(a, b, acc7[ct], 0, 0, 0);
    }
  }

  // C/D layout: col = lane&15, row = (lane>>4)*4 + reg
  #pragma unroll
  for (int ct = 0; ct < 7; ++ct){
    int col = ct*16 + lr;
    float bvv = bc[col];
    #pragma unroll
    for (int r = 0; r < 4; ++r){
      int nl = w*16 + lk*4 + r;
      int gm = m0 + nl;
      if (gm < n_nodes){
        __half hv = __float2half(acc7[ct][r] + bvv);
        int gn = idxs[nl];
        if (col < 64) tf16[(size_t)gn*64 + col] = hv;
        else {
          int cg = col - 64;
          int p = cg >= 24;
          P[(size_t)p*2400000 + (size_t)gn*24 + (cg - p*24)] = hv;
        }
      }
    }
  }
}

// ---- zero int buffer ----
__global__ void k_zeroi(int* __restrict__ p, int n){
  int t = blockIdx.x*blockDim.x + threadIdx.x;
  if (t < n) p[t] = 0;
}

// ---- histograms: dst (both p) + tgt (both p) ----
__global__ void k_hist3(const int* __restrict__ d0, const int* __restrict__ d1,
                        const int* __restrict__ t0, const int* __restrict__ t1,
                        int* __restrict__ counts, int* __restrict__ cntt){
  int e = blockIdx.x*blockDim.x + threadIdx.x;
  if (e < NE) atomicAdd(&counts[d0[e]], 1);
  else if (e < 2*NE) atomicAdd(&counts[NG + d1[e-NE]], 1);
  else if (e < 2*NE + NB) atomicAdd(&cntt[t0[e-2*NE]], 1);
  else if (e < 2*NE + 2*NB) atomicAdd(&cntt[NG + t1[e-2*NE-NB]], 1);
}

// ---- exclusive scan over 16384 counts; also zero cursors ----
__global__ __launch_bounds__(1024) void k_scan(const int* __restrict__ counts,
                                               int* __restrict__ offs,
                                               int* __restrict__ curs){
  __shared__ int lds[1024];
  int t = threadIdx.x;
  int base = t*16;
  int v[16]; int sum = 0;
  #pragma unroll
  for (int i = 0; i < 16; ++i){ v[i] = counts[base+i]; sum += v[i]; }
  lds[t] = sum;
  __syncthreads();
  for (int off = 1; off < 1024; off <<= 1){
    int x = (t >= off) ? lds[t-off] : 0;
    __syncthreads();
    lds[t] += x;
    __syncthreads();
  }
  int excl = lds[t] - sum;
  #pragma unroll
  for (int i = 0; i < 16; ++i){ offs[base+i] = excl; excl += v[i]; curs[base+i] = 0; }
  if (t == 1023) offs[2*NG] = excl;
}

// ---- scatter both metapaths' edges into dst-sorted order ----
__global__ void k_scatter2(const int* __restrict__ m0, const int* __restrict__ d0,
                           const int* __restrict__ m1, const int* __restrict__ d1,
                           const int* __restrict__ offs, int* __restrict__ curs,
                           int4* __restrict__ sorted){
  int e = blockIdx.x*blockDim.x + threadIdx.x;
  if (e >= 2*NE) return;
  const int* mp; int d;
  if (e < NE){ mp = m0 + (size_t)e*3; d = d0[e]; }
  else { mp = m1 + (size_t)(e-NE)*3; d = NG + d1[e-NE]; }
  int pos = offs[d] + atomicAdd(&curs[d], 1);
  sorted[pos] = make_int4(mp[0], mp[1], mp[2], 0);
}

// ---- fused per-segment softmax-agg; stores elu(ft) f16; s in phase A ----
__global__ __launch_bounds__(64) void k_seg(const __half* __restrict__ tf16,
                                            const __half* __restrict__ P,
                                            const int4* __restrict__ sorted,
                                            const int* __restrict__ offs,
                                            const float* __restrict__ finals,
                                            __half* __restrict__ ft16o){
  int bid = blockIdx.x;
  int p = bid >> 13;
  int lane = threadIdx.x;
  int hw = lane >> 5, j = lane & 31;
  int start = offs[bid], end = offs[bid+1];
  __half2* ftw = (__half2*)(ft16o + (size_t)bid*512);
  if (start == end){
    #pragma unroll
    for (int kk = 0; kk < 4; ++kk) ftw[(hw*4+kk)*32 + j] = __floats2half2_rn(0.f, 0.f);
    return;
  }
  const float2* F2 = (const float2*)(finals + p*192);
  float2 f0 = F2[j], f1 = F2[32 + j];
  const __half2* tfh = (const __half2*)tf16;
  const __half* Pp = P + (size_t)p*2400000;

  __shared__ int4 ndb[64];
  __shared__ float wb[64][8];

  float sA[8], ur[8], ui[8];
  #pragma unroll
  for (int k = 0; k < 8; ++k){ sA[k] = 0.f; ur[k] = 0.f; ui[k] = 0.f; }

  for (int c = start; c < end; c += 64){
    int n = end - c; if (n > 64) n = 64;
    if (lane < n){
      int4 nd = sorted[c + lane];
      ndb[lane] = nd;
      float4 rA = *(const float4*)(Pp + (size_t)nd.x*24);
      float4 rB = *(const float4*)(Pp + (size_t)nd.y*24 + 8);
      float4 rC = *(const float4*)(Pp + (size_t)nd.z*24 + 16);
      const __half2* ha = (const __half2*)&rA;
      const __half2* hb = (const __half2*)&rB;
      const __half2* hc = (const __half2*)&rC;
      float w[8];
      #pragma unroll
      for (int m = 0; m < 4; ++m){
        float2 va = __half22float2(ha[m]);
        float2 vb = __half22float2(hb[m]);
        float2 vc = __half22float2(hc[m]);
        float x0 = va.x + vb.x + vc.x;
        float x1 = va.y + vb.y + vc.y;
        x0 = x0 > 0.f ? x0 : 0.01f*x0;
        x1 = x1 > 0.f ? x1 : 0.01f*x1;
        w[2*m]   = __expf(x0);
        w[2*m+1] = __expf(x1);
      }
      #pragma unroll
      for (int k = 0; k < 8; ++k) sA[k] += w[k];
      *(float4*)&wb[lane][0] = make_float4(w[0], w[1], w[2], w[3]);
      *(float4*)&wb[lane][4] = make_float4(w[4], w[5], w[6], w[7]);
    }
    __syncthreads();
    int cend = c + n;
    for (int i = c + hw; i < cend; i += 2){
      int e = i - c;
      int4 nd = ndb[e];
      float4 wlo = *(const float4*)&wb[e][0];
      float4 whi = *(const float4*)&wb[e][4];
      float2 v0 = __half22float2(tfh[(size_t)nd.x*32 + j]);
      float2 v1 = __half22float2(tfh[(size_t)nd.y*32 + j]);
      float2 v2 = __half22float2(tfh[(size_t)nd.z*32 + j]);
      float hre = (v0.x*f0.x - v0.y*f0.y) + (v1.x*f1.x - v1.y*f1.y) + v2.x;
      float him = (v0.x*f0.y + v0.y*f0.x) + (v1.x*f1.y + v1.y*f1.x) + v2.y;
      ur[0] += wlo.x*hre; ui[0] += wlo.x*him;
      ur[1] += wlo.y*hre; ui[1] += wlo.y*him;
      ur[2] += wlo.z*hre; ui[2] += wlo.z*him;
      ur[3] += wlo.w*hre; ui[3] += wlo.w*him;
      ur[4] += whi.x*hre; ui[4] += whi.x*him;
      ur[5] += whi.y*hre; ui[5] += whi.y*him;
      ur[6] += whi.z*hre; ui[6] += whi.z*him;
      ur[7] += whi.w*hre; ui[7] += whi.w*him;
    }
    __syncthreads();
  }
  #pragma unroll
  for (int k = 0; k < 8; ++k){
    ur[k] += __shfl_xor(ur[k], 32);
    ui[k] += __shfl_xor(ui[k], 32);
    float v = sA[k];
    #pragma unroll
    for (int mask = 1; mask < 64; mask <<= 1) v += __shfl_xor(v, mask);
    sA[k] = v;
  }
  #pragma unroll
  for (int kk = 0; kk < 4; ++kk){
    int k = hw*4 + kk;
    float inv = 1.f / (3.f * sA[k]);
    float re = ur[k]*inv, im = ui[k]*inv;
    re = re > 0.f ? re : expm1f(re);    // elu fused
    im = im > 0.f ? im : expm1f(im);
    ftw[k*32 + j] = __floats2half2_rn(re, im);
  }
}

// ---- s1 via MFMA (validated layout): no LDS, fragments from global ----
__global__ __launch_bounds__(256) void k_s1g(const __half* __restrict__ ft16o,
                                             const int* __restrict__ cntt,
                                             const __half* __restrict__ fc1h,
                                             const float* __restrict__ fc1_b,
                                             float* __restrict__ acc_p){
  int bid = blockIdx.x;
  int p  = bid >> 8;
  int rb = bid & 255;
  int t = threadIdx.x;
  int w = t >> 6, l = t & 63;
  int rowbase = rb*32 + (w & 1)*16;
  int colbase = (w >> 1)*64;
  int lr = l & 15, lk = l >> 4;

  const half8v* Ab = (const half8v*)(ft16o + ((size_t)p*NG + rowbase)*512);
  f32x4 acc[4] = {{0.f,0.f,0.f,0.f},{0.f,0.f,0.f,0.f},
                  {0.f,0.f,0.f,0.f},{0.f,0.f,0.f,0.f}};

  #pragma unroll 4
  for (int kk = 0; kk < 16; ++kk){
    half8v a = Ab[(size_t)lr*64 + kk*4 + lk];
    #pragma unroll
    for (int ct = 0; ct < 4; ++ct){
      const half8v* Bb = (const half8v*)(fc1h + (size_t)(colbase + ct*16 + lr)*512);
      half8v b = Bb[kk*4 + lk];
      acc[ct] = __builtin_amdgcn_mfma_f32_16x16x32_f16(a, b, acc[ct], 0, 0, 0);
    }
  }

  float cf[4];
  #pragma unroll
  for (int r = 0; r < 4; ++r)
    cf[r] = (float)cntt[p*NG + rowbase + lk*4 + r];
  #pragma unroll
  for (int ct = 0; ct < 4; ++ct){
    int col = colbase + ct*16 + lr;
    float bv = fc1_b[col];
    float sv = 0.f;
    #pragma unroll
    for (int r = 0; r < 4; ++r)
      sv += cf[r] * tanhf(acc[ct][r] + bv);
    sv += __shfl_xor(sv, 16);
    sv += __shfl_xor(sv, 32);
    if (l < 16) atomicAdd(&acc_p[p*128 + col], sv);
  }
}

// ---- beta softmax over 2 metapaths ----
__global__ void k_beta(const float* __restrict__ acc, const float* __restrict__ fc2_w,
                       float* __restrict__ beta){
  int t = threadIdx.x;  // 64
  float s0 = acc[t]*fc2_w[t] + acc[t+64]*fc2_w[t+64];
  float s1 = acc[128+t]*fc2_w[t] + acc[192+t]*fc2_w[t+64];
  #pragma unroll
  for (int mask = 1; mask < 64; mask <<= 1){
    s0 += __shfl_xor(s0, mask, 64);
    s1 += __shfl_xor(s1, mask, 64);
  }
  if (t == 0){
    float z0 = s0 / (float)NB, z1 = s1 / (float)NB;
    float mz = fmaxf(z0, z1);
    float e0 = expf(z0 - mz), e1 = expf(z1 - mz);
    float inv = 1.f / (e0 + e1);
    beta[0] = e0*inv; beta[1] = e1*inv;
  }
}

// ---- hagg + logits (ft already elu'd, f16) ----
__global__ void k_final(const __half* __restrict__ ft0, const __half* __restrict__ ft1,
                        const int* __restrict__ tgt0, const int* __restrict__ tgt1,
                        const float* __restrict__ beta, const float* __restrict__ fc_w,
                        const float* __restrict__ fc_b, float* __restrict__ d_out){
  __shared__ float lds[512];
  int b = blockIdx.x, t = threadIdx.x;  // 512 threads
  float b0 = beta[0], b1 = beta[1];
  int g0 = tgt0[b], g1 = tgt1[b];
  float v0 = __half2float(ft0[(size_t)g0*512 + t]);
  float v1 = __half2float(ft1[(size_t)g1*512 + t]);
  float h = b0*v0 + b1*v1;
  lds[t] = h;
  d_out[(size_t)NB*OUTD + (size_t)b*512 + t] = h;
  __syncthreads();
  int o = t >> 5, j = t & 31;
  float s = 0.f;
  const float* w = fc_w + o*512;
  for (int d = j; d < 512; d += 32) s += lds[d]*w[d];
  #pragma unroll
  for (int mask = 1; mask < 32; mask <<= 1) s += __shfl_xor(s, mask, 32);
  if (j == 0) d_out[(size_t)b*OUTD + o] = s + fc_b[o];
}

extern "C" void kernel_launch(void* const* d_in, const int* in_sizes, int n_in,
                              void* d_out, int out_size, void* d_ws, size_t ws_size,
                              hipStream_t stream){
  const float* feat0  = (const float*)d_in[0];
  const float* feat1  = (const float*)d_in[1];
  const float* W0     = (const float*)d_in[2];
  const float* b0     = (const float*)d_in[3];
  const float* W1     = (const float*)d_in[4];
  const float* b1     = (const float*)d_in[5];
  const float* r_vec  = (const float*)d_in[6];
  const float* attn0  = (const float*)d_in[7];
  const float* attn1  = (const float*)d_in[8];
  const float* fc1_w  = (const float*)d_in[9];
  const float* fc1_b  = (const float*)d_in[10];
  const float* fc2_w  = (const float*)d_in[11];
  const float* fc_w   = (const float*)d_in[12];
  const float* fc_b   = (const float*)d_in[13];
  const int*   idx0   = (const int*)d_in[14];
  const int*   idx1   = (const int*)d_in[15];
  const int*   mpi0   = (const int*)d_in[16];
  const int*   mdst0  = (const int*)d_in[17];
  const int*   mtgt0  = (const int*)d_in[18];
  const int*   mpi1   = (const int*)d_in[19];
  const int*   mdst1  = (const int*)d_in[20];
  const int*   mtgt1  = (const int*)d_in[21];

  float* ws      = (float*)d_ws;
  __half* tf16   = (__half*)(ws + OFF_TF16);
  float* finals  = ws + OFF_FINALS;
  float* acc     = ws + OFF_ACC;
  float* beta    = ws + OFF_BETA;
  __half* wc0    = (__half*)(ws + OFF_WC0);
  __half* wc1    = (__half*)(ws + OFF_WC1);
  float* bc0     = ws + OFF_BC0;
  float* bc1     = ws + OFF_BC1;
  __half* fc1h   = (__half*)(ws + OFF_FC1H);
  __half* P      = (__half*)(ws + OFF_P);
  int4*  sorted  = (int4*)(ws + OFF_SORTED);
  int*   counts  = (int*)(ws + OFF_COUNTS);
  int*   cntt    = (int*)(ws + OFF_CNTT);
  int*   curs    = (int*)(ws + OFF_CURS);
  int*   offs    = (int*)(ws + OFF_OFFS);
  __half* ft16o  = (__half*)(ws + OFF_FT16);
  __half* ft0h   = ft16o;
  __half* ft1h   = ft16o + (size_t)NG*512;

  k_prep0<<<1, 64, 0, stream>>>(r_vec, finals, acc, beta);
  k_wcat<<<288, 128, 0, stream>>>(r_vec, attn0, attn1, W0, b0, W1, b1, fc1_w,
                                  wc0, bc0, wc1, bc1, fc1h);
  k_zeroi<<<128, 256, 0, stream>>>(counts, 4*NG);
  k_hist3<<<(2*NE + 2*NB + 255)/256, 256, 0, stream>>>(mdst0, mdst1, mtgt0, mtgt1,
                                                       counts, cntt);
  k_scan<<<1, 1024, 0, stream>>>(counts, offs, curs);
  k_scatter2<<<(2*NE + 255)/256, 256, 0, stream>>>(mpi0, mdst0, mpi1, mdst1,
                                                   offs, curs, sorted);

  k_tform<<<(NT0 + 63)/64 + (NT1 + 63)/64, 256, 0, stream>>>(
      feat0, idx0, feat1, idx1, wc0, bc0, wc1, bc1, tf16, P);

  k_seg<<<2*NG, 64, 0, stream>>>(tf16, P, sorted, offs, finals, ft16o);

  k_s1g<<<512, 256, 0, stream>>>(ft16o, cntt, fc1h, fc1_b, acc);
  k_beta<<<1, 64, 0, stream>>>(acc, fc2_w, beta);
  k_final<<<NB, 512, 0, stream>>>(ft0h, ft1h, mtgt0, mtgt1, beta, fc_w, fc_b,
                                  (float*)d_out);
}

// Round 12
// 225.564 us; speedup vs baseline: 1.2212x; 1.0214x over previous
//
#include <hip/hip_runtime.h>
#include <hip/hip_fp16.h>
#include <math.h>

#define NNODES 100000
#define NT0 60000
#define NT1 40000
#define FD0 128
#define FD1 64
#define HID 64
#define HEADS 8
#define OUTD 16
#define AVEC 128
#define NE 250000
#define NG 8192
#define NB 8192

typedef _Float16 half8v __attribute__((ext_vector_type(8)));
typedef float f32x4 __attribute__((ext_vector_type(4)));

// workspace layout (float offsets)
#define OFF_TF16    0ull          // 3,200,000
#define OFF_FINALS  3200000ull    // 512
#define OFF_ACC     3200512ull    // 256
#define OFF_BETA    3200768ull    // 256
#define OFF_WC0     3201024ull    // 7,168  (f16 [112][128])
#define OFF_WC1     3208192ull    // 3,584  (f16 [112][64])
#define OFF_BC0     3211776ull    // 128
#define OFF_BC1     3211904ull    // 128
#define OFF_FC1H    3212032ull    // 32,768 (f16 [128][512])
#define OFF_P       3244800ull    // 2,400,000 (f16 P[2][100000][24])
#define OFF_SORTED  5644800ull    // 2,000,000 (500,000 int4; byte off % 16 == 0)
#define OFF_COUNTS  7644800ull    // 16,384 ints
#define OFF_CNTT    7661184ull    // 16,384 ints (contiguous with COUNTS)
#define OFF_CURS    7677568ull    // 16,384 ints
#define OFF_OFFS    7693952ull    // 16,640 ints (16,385 used)
#define OFF_FT16    7710592ull    // 4,194,304 (f16 2*NG*512)
// total = 11,904,896 floats = 47.6 MB

// ---- compute one rotation float2 for (pi, pair j) from r_vec ----
__device__ __forceinline__ float2 rot_pair(const float* r_vec, int pi, int j){
  const float2* rv = (const float2*)r_vec;
  int rel = pi >= 3 ? 1 : 0;
  float2 r = rv[rel*32 + j];
  float n = rsqrtf(r.x*r.x + r.y*r.y);
  r.x *= n; r.y *= n;
  float2 rf = make_float2(r.x, -r.y);           // conj
  int pos = pi - rel*3;
  if (pos == 2) return make_float2(1.f, 0.f);
  if (pos == 1) return rf;
  return make_float2(rf.x*r.x - rf.y*r.y, rf.x*r.y + rf.y*r.x);  // rf * r
}

// ---- wcat: Wcat rows + fc1h + (block 288) finals/acc/beta ----
// grid 289 x 128: 0..111 -> wc0 rows, 112..223 -> wc1 rows, 224..287 -> fc1h,
// 288 -> prep (finals + zero acc/beta)
__global__ __launch_bounds__(128) void k_wcat(const float* __restrict__ r_vec,
     const float* __restrict__ attn0, const float* __restrict__ attn1,
     const float* __restrict__ W0v, const float* __restrict__ b0v,
     const float* __restrict__ W1v, const float* __restrict__ b1v,
     const float* __restrict__ fc1_w,
     __half* __restrict__ wc0, float* __restrict__ bc0,
     __half* __restrict__ wc1, float* __restrict__ bc1,
     __half* __restrict__ fc1h,
     float* __restrict__ finals, float* __restrict__ acc, float* __restrict__ beta){
  int bid = blockIdx.x;
  int t = threadIdx.x;
  if (bid == 288){
    if (t < 32){
      float2* F = (float2*)finals;
      #pragma unroll
      for (int pi = 0; pi < 6; ++pi) F[pi*32 + t] = rot_pair(r_vec, pi, t);
    }
    for (int q = t; q < 256; q += 128) acc[q] = 0.f;
    if (t < 2) beta[t] = 0.f;
    return;
  }
  if (bid >= 224){
    int base = (bid - 224)*1024;
    for (int i = t; i < 1024; i += 128)
      fc1h[base + i] = __float2half(fc1_w[base + i]);
    return;
  }
  int type = bid >= 112;
  int c = bid - type*112;
  int F = type ? FD1 : FD0;
  const float* W  = type ? W1v : W0v;
  const float* bv = type ? b1v : b0v;
  __half* wc = type ? wc1 : wc0;
  float* bc  = type ? bc1 : bc0;

  if (c < 64){
    for (int f = t; f < F; f += 128) wc[(size_t)c*F + f] = __float2half(W[(size_t)c*F + f]);
    if (t == 0) bc[c] = bv[c];
    return;
  }
  __shared__ float a[64];
  int cg = c - 64;          // 0..47
  int pi = cg >> 3, k = cg & 7;
  if (t < 32){
    float2 f = rot_pair(r_vec, pi, t);
    const float* at = (pi >= 3) ? attn1 : attn0;
    float a0 = at[k*64 + 2*t], a1 = at[k*64 + 2*t + 1];
    a[2*t]     = (f.x*a0 + f.y*a1) * (1.f/3.f);
    a[2*t + 1] = (f.x*a1 - f.y*a0) * (1.f/3.f);
  }
  __syncthreads();
  for (int f = t; f < F; f += 128){
    float s = 0.f;
    #pragma unroll 16
    for (int d = 0; d < 64; ++d) s += a[d] * W[(size_t)d*F + f];
    wc[(size_t)c*F + f] = __float2half(s);
  }
  if (t == 0){
    float s = 0.f;
    #pragma unroll 16
    for (int d = 0; d < 64; ++d) s += a[d] * bv[d];
    bc[c] = s;
  }
}

// ---- fused transform+P via MFMA; LDS-staged coalesced output ----
__global__ __launch_bounds__(256) void k_tform(const float* __restrict__ feat0,
      const int* __restrict__ idx0, const float* __restrict__ feat1,
      const int* __restrict__ idx1,
      const __half* __restrict__ wc0, const float* __restrict__ bc0,
      const __half* __restrict__ wc1, const float* __restrict__ bc1,
      __half* __restrict__ tf16, __half* __restrict__ P){
  const int nb0 = (NT0 + 63)/64;
  int bid = blockIdx.x;
  const float* feat; const int* idx; const __half* wc; const float* bc;
  int n_nodes, F, m0;
  if (bid < nb0){ feat=feat0; idx=idx0; wc=wc0; bc=bc0; n_nodes=NT0; F=FD0; m0=bid*64; }
  else { feat=feat1; idx=idx1; wc=wc1; bc=bc1; n_nodes=NT1; F=FD1; m0=(bid-nb0)*64; }
  __shared__ int idxs[64];
  __shared__ __half outs[64][120];   // [node][col], 240B row stride
  int t = threadIdx.x;
  if (t < 64){
    int gm = m0 + t; if (gm > n_nodes - 1) gm = n_nodes - 1;
    idxs[t] = idx[gm];
  }
  __syncthreads();
  int w = t >> 6, l = t & 63;
  int lr = l & 15, lk = l >> 4;
  int gr = m0 + w*16 + lr; if (gr > n_nodes - 1) gr = n_nodes - 1;
  const float* arow = feat + (size_t)gr*F;

  f32x4 acc7[7];
  #pragma unroll
  for (int ct = 0; ct < 7; ++ct) acc7[ct] = (f32x4){0.f,0.f,0.f,0.f};

  int nk = F >> 5;
  for (int kk = 0; kk < nk; ++kk){
    int koff = kk*32 + lk*8;
    float4 ua = *(const float4*)(arow + koff);
    float4 ub = *(const float4*)(arow + koff + 4);
    half8v a = {(_Float16)ua.x,(_Float16)ua.y,(_Float16)ua.z,(_Float16)ua.w,
                (_Float16)ub.x,(_Float16)ub.y,(_Float16)ub.z,(_Float16)ub.w};
    #pragma unroll
    for (int ct = 0; ct < 7; ++ct){
      half8v b = *(const half8v*)(wc + (size_t)(ct*16 + lr)*F + koff);
      acc7[ct] = __builtin_amdgcn_mfma_f32_16x16x32_f16(a, b, acc7[ct], 0, 0, 0);
    }
  }

  // C/D layout: col = lane&15, row = (lane>>4)*4 + reg -> stage in LDS
  #pragma unroll
  for (int ct = 0; ct < 7; ++ct){
    int col = ct*16 + lr;
    float bvv = bc[col];
    #pragma unroll
    for (int r = 0; r < 4; ++r){
      int nl = w*16 + lk*4 + r;
      outs[nl][col] = __float2half(acc7[ct][r] + bvv);
    }
  }
  __syncthreads();
  // tf16: 64 rows x 8 x 16B chunks, coalesced
  #pragma unroll
  for (int u = t; u < 512; u += 256){
    int n = u >> 3, c = u & 7;
    if (m0 + n < n_nodes){
      uint4 v = *(uint4*)&outs[n][c*8];
      *(uint4*)&tf16[(size_t)idxs[n]*64 + c*8] = v;
    }
  }
  // P: 2 paths x 64 rows x 3 x 16B chunks
  for (int u = t; u < 384; u += 256){
    int pp = u >= 192;
    int rr = u - pp*192;
    int n = rr / 3, c = rr - n*3;
    if (m0 + n < n_nodes){
      uint4 v = *(uint4*)&outs[n][64 + pp*24 + c*8];
      *(uint4*)&P[(size_t)pp*2400000 + (size_t)idxs[n]*24 + c*8] = v;
    }
  }
}

// ---- histograms: dst (both p) + tgt (both p) ----
__global__ void k_hist3(const int* __restrict__ d0, const int* __restrict__ d1,
                        const int* __restrict__ t0, const int* __restrict__ t1,
                        int* __restrict__ counts, int* __restrict__ cntt){
  int e = blockIdx.x*blockDim.x + threadIdx.x;
  if (e < NE) atomicAdd(&counts[d0[e]], 1);
  else if (e < 2*NE) atomicAdd(&counts[NG + d1[e-NE]], 1);
  else if (e < 2*NE + NB) atomicAdd(&cntt[t0[e-2*NE]], 1);
  else if (e < 2*NE + 2*NB) atomicAdd(&cntt[NG + t1[e-2*NE-NB]], 1);
}

// ---- exclusive scan over 16384 counts; also zero cursors ----
__global__ __launch_bounds__(1024) void k_scan(const int* __restrict__ counts,
                                               int* __restrict__ offs,
                                               int* __restrict__ curs){
  __shared__ int lds[1024];
  int t = threadIdx.x;
  int base = t*16;
  int v[16]; int sum = 0;
  #pragma unroll
  for (int i = 0; i < 16; ++i){ v[i] = counts[base+i]; sum += v[i]; }
  lds[t] = sum;
  __syncthreads();
  for (int off = 1; off < 1024; off <<= 1){
    int x = (t >= off) ? lds[t-off] : 0;
    __syncthreads();
    lds[t] += x;
    __syncthreads();
  }
  int excl = lds[t] - sum;
  #pragma unroll
  for (int i = 0; i < 16; ++i){ offs[base+i] = excl; excl += v[i]; curs[base+i] = 0; }
  if (t == 1023) offs[2*NG] = excl;
}

// ---- scatter both metapaths' edges into dst-sorted order ----
__global__ void k_scatter2(const int* __restrict__ m0, const int* __restrict__ d0,
                           const int* __restrict__ m1, const int* __restrict__ d1,
                           const int* __restrict__ offs, int* __restrict__ curs,
                           int4* __restrict__ sorted){
  int e = blockIdx.x*blockDim.x + threadIdx.x;
  if (e >= 2*NE) return;
  const int* mp; int d;
  if (e < NE){ mp = m0 + (size_t)e*3; d = d0[e]; }
  else { mp = m1 + (size_t)(e-NE)*3; d = NG + d1[e-NE]; }
  int pos = offs[d] + atomicAdd(&curs[d], 1);
  sorted[pos] = make_int4(mp[0], mp[1], mp[2], 0);
}

// ---- fused per-segment softmax-agg; 2 independent waves per block ----
__global__ __launch_bounds__(128) void k_seg(const __half* __restrict__ tf16,
                                             const __half* __restrict__ P,
                                             const int4* __restrict__ sorted,
                                             const int* __restrict__ offs,
                                             const float* __restrict__ finals,
                                             __half* __restrict__ ft16o){
  __shared__ int4 ndb[2][64];
  __shared__ float wb[2][64][8];
  int wv = threadIdx.x >> 6;
  int seg = blockIdx.x*2 + wv;           // grid NG blocks -> 2*NG segments
  int p = seg >> 13;
  int lane = threadIdx.x & 63;
  int hw = lane >> 5, j = lane & 31;
  int start = offs[seg], end = offs[seg+1];
  __half2* ftw = (__half2*)(ft16o + (size_t)seg*512);
  if (start == end){
    #pragma unroll
    for (int kk = 0; kk < 4; ++kk) ftw[(hw*4+kk)*32 + j] = __floats2half2_rn(0.f, 0.f);
    return;
  }
  const float2* F2 = (const float2*)(finals + p*192);
  float2 f0 = F2[j], f1 = F2[32 + j];
  const __half2* tfh = (const __half2*)tf16;
  const __half* Pp = P + (size_t)p*2400000;
  int4* nb = ndb[wv];
  float (*wbp)[8] = wb[wv];

  float sA[8], ur[8], ui[8];
  #pragma unroll
  for (int k = 0; k < 8; ++k){ sA[k] = 0.f; ur[k] = 0.f; ui[k] = 0.f; }

  for (int c = start; c < end; c += 64){
    int n = end - c; if (n > 64) n = 64;
    // ---- phase A: logits + s accumulation (lane-per-edge) ----
    if (lane < n){
      int4 nd = sorted[c + lane];
      nb[lane] = nd;
      float4 rA = *(const float4*)(Pp + (size_t)nd.x*24);
      float4 rB = *(const float4*)(Pp + (size_t)nd.y*24 + 8);
      float4 rC = *(const float4*)(Pp + (size_t)nd.z*24 + 16);
      const __half2* ha = (const __half2*)&rA;
      const __half2* hb = (const __half2*)&rB;
      const __half2* hc = (const __half2*)&rC;
      float w[8];
      #pragma unroll
      for (int m = 0; m < 4; ++m){
        float2 va = __half22float2(ha[m]);
        float2 vb = __half22float2(hb[m]);
        float2 vc = __half22float2(hc[m]);
        float x0 = va.x + vb.x + vc.x;
        float x1 = va.y + vb.y + vc.y;
        x0 = x0 > 0.f ? x0 : 0.01f*x0;
        x1 = x1 > 0.f ? x1 : 0.01f*x1;
        w[2*m]   = __expf(x0);
        w[2*m+1] = __expf(x1);
      }
      #pragma unroll
      for (int k = 0; k < 8; ++k) sA[k] += w[k];
      *(float4*)&wbp[lane][0] = make_float4(w[0], w[1], w[2], w[3]);
      *(float4*)&wbp[lane][4] = make_float4(w[4], w[5], w[6], w[7]);
    }
    // wave-internal LDS sync (no cross-wave barrier: trip counts differ)
    asm volatile("s_waitcnt lgkmcnt(0)" ::: "memory");
    __builtin_amdgcn_sched_barrier(0);
    // ---- phase B: weighted aggregation (half-wave per edge) ----
    int cend = c + n;
    for (int i = c + hw; i < cend; i += 2){
      int e = i - c;
      int4 nd = nb[e];
      float4 wlo = *(const float4*)&wbp[e][0];
      float4 whi = *(const float4*)&wbp[e][4];
      float2 v0 = __half22float2(tfh[(size_t)nd.x*32 + j]);
      float2 v1 = __half22float2(tfh[(size_t)nd.y*32 + j]);
      float2 v2 = __half22float2(tfh[(size_t)nd.z*32 + j]);
      float hre = (v0.x*f0.x - v0.y*f0.y) + (v1.x*f1.x - v1.y*f1.y) + v2.x;
      float him = (v0.x*f0.y + v0.y*f0.x) + (v1.x*f1.y + v1.y*f1.x) + v2.y;
      ur[0] += wlo.x*hre; ui[0] += wlo.x*him;
      ur[1] += wlo.y*hre; ui[1] += wlo.y*him;
      ur[2] += wlo.z*hre; ui[2] += wlo.z*him;
      ur[3] += wlo.w*hre; ui[3] += wlo.w*him;
      ur[4] += whi.x*hre; ui[4] += whi.x*him;
      ur[5] += whi.y*hre; ui[5] += whi.y*him;
      ur[6] += whi.z*hre; ui[6] += whi.z*him;
      ur[7] += whi.w*hre; ui[7] += whi.w*him;
    }
    // reads must land before next chunk's phase A overwrites
    asm volatile("s_waitcnt lgkmcnt(0)" ::: "memory");
    __builtin_amdgcn_sched_barrier(0);
  }
  #pragma unroll
  for (int k = 0; k < 8; ++k){
    ur[k] += __shfl_xor(ur[k], 32);
    ui[k] += __shfl_xor(ui[k], 32);
    float v = sA[k];
    #pragma unroll
    for (int mask = 1; mask < 64; mask <<= 1) v += __shfl_xor(v, mask);
    sA[k] = v;
  }
  #pragma unroll
  for (int kk = 0; kk < 4; ++kk){
    int k = hw*4 + kk;
    float inv = 1.f / (3.f * sA[k]);
    float re = ur[k]*inv, im = ui[k]*inv;
    re = re > 0.f ? re : expm1f(re);    // elu fused
    im = im > 0.f ? im : expm1f(im);
    ftw[k*32 + j] = __floats2half2_rn(re, im);
  }
}

// ---- s1 via MFMA (validated layout): no LDS, fragments from global ----
__global__ __launch_bounds__(256) void k_s1g(const __half* __restrict__ ft16o,
                                             const int* __restrict__ cntt,
                                             const __half* __restrict__ fc1h,
                                             const float* __restrict__ fc1_b,
                                             float* __restrict__ acc_p){
  int bid = blockIdx.x;
  int p  = bid >> 8;
  int rb = bid & 255;
  int t = threadIdx.x;
  int w = t >> 6, l = t & 63;
  int rowbase = rb*32 + (w & 1)*16;
  int colbase = (w >> 1)*64;
  int lr = l & 15, lk = l >> 4;

  const half8v* Ab = (const half8v*)(ft16o + ((size_t)p*NG + rowbase)*512);
  f32x4 acc[4] = {{0.f,0.f,0.f,0.f},{0.f,0.f,0.f,0.f},
                  {0.f,0.f,0.f,0.f},{0.f,0.f,0.f,0.f}};

  #pragma unroll 4
  for (int kk = 0; kk < 16; ++kk){
    half8v a = Ab[(size_t)lr*64 + kk*4 + lk];
    #pragma unroll
    for (int ct = 0; ct < 4; ++ct){
      const half8v* Bb = (const half8v*)(fc1h + (size_t)(colbase + ct*16 + lr)*512);
      half8v b = Bb[kk*4 + lk];
      acc[ct] = __builtin_amdgcn_mfma_f32_16x16x32_f16(a, b, acc[ct], 0, 0, 0);
    }
  }

  float cf[4];
  #pragma unroll
  for (int r = 0; r < 4; ++r)
    cf[r] = (float)cntt[p*NG + rowbase + lk*4 + r];
  #pragma unroll
  for (int ct = 0; ct < 4; ++ct){
    int col = colbase + ct*16 + lr;
    float bv = fc1_b[col];
    float sv = 0.f;
    #pragma unroll
    for (int r = 0; r < 4; ++r)
      sv += cf[r] * tanhf(acc[ct][r] + bv);
    sv += __shfl_xor(sv, 16);
    sv += __shfl_xor(sv, 32);
    if (l < 16) atomicAdd(&acc_p[p*128 + col], sv);
  }
}

// ---- beta softmax over 2 metapaths ----
__global__ void k_beta(const float* __restrict__ acc, const float* __restrict__ fc2_w,
                       float* __restrict__ beta){
  int t = threadIdx.x;  // 64
  float s0 = acc[t]*fc2_w[t] + acc[t+64]*fc2_w[t+64];
  float s1 = acc[128+t]*fc2_w[t] + acc[192+t]*fc2_w[t+64];
  #pragma unroll
  for (int mask = 1; mask < 64; mask <<= 1){
    s0 += __shfl_xor(s0, mask, 64);
    s1 += __shfl_xor(s1, mask, 64);
  }
  if (t == 0){
    float z0 = s0 / (float)NB, z1 = s1 / (float)NB;
    float mz = fmaxf(z0, z1);
    float e0 = expf(z0 - mz), e1 = expf(z1 - mz);
    float inv = 1.f / (e0 + e1);
    beta[0] = e0*inv; beta[1] = e1*inv;
  }
}

// ---- hagg + logits (ft already elu'd, f16) ----
__global__ void k_final(const __half* __restrict__ ft0, const __half* __restrict__ ft1,
                        const int* __restrict__ tgt0, const int* __restrict__ tgt1,
                        const float* __restrict__ beta, const float* __restrict__ fc_w,
                        const float* __restrict__ fc_b, float* __restrict__ d_out){
  __shared__ float lds[512];
  int b = blockIdx.x, t = threadIdx.x;  // 512 threads
  float b0 = beta[0], b1 = beta[1];
  int g0 = tgt0[b], g1 = tgt1[b];
  float v0 = __half2float(ft0[(size_t)g0*512 + t]);
  float v1 = __half2float(ft1[(size_t)g1*512 + t]);
  float h = b0*v0 + b1*v1;
  lds[t] = h;
  d_out[(size_t)NB*OUTD + (size_t)b*512 + t] = h;
  __syncthreads();
  int o = t >> 5, j = t & 31;
  float s = 0.f;
  const float* w = fc_w + o*512;
  for (int d = j; d < 512; d += 32) s += lds[d]*w[d];
  #pragma unroll
  for (int mask = 1; mask < 32; mask <<= 1) s += __shfl_xor(s, mask, 32);
  if (j == 0) d_out[(size_t)b*OUTD + o] = s + fc_b[o];
}

extern "C" void kernel_launch(void* const* d_in, const int* in_sizes, int n_in,
                              void* d_out, int out_size, void* d_ws, size_t ws_size,
                              hipStream_t stream){
  const float* feat0  = (const float*)d_in[0];
  const float* feat1  = (const float*)d_in[1];
  const float* W0     = (const float*)d_in[2];
  const float* b0     = (const float*)d_in[3];
  const float* W1     = (const float*)d_in[4];
  const float* b1     = (const float*)d_in[5];
  const float* r_vec  = (const float*)d_in[6];
  const float* attn0  = (const float*)d_in[7];
  const float* attn1  = (const float*)d_in[8];
  const float* fc1_w  = (const float*)d_in[9];
  const float* fc1_b  = (const float*)d_in[10];
  const float* fc2_w  = (const float*)d_in[11];
  const float* fc_w   = (const float*)d_in[12];
  const float* fc_b   = (const float*)d_in[13];
  const int*   idx0   = (const int*)d_in[14];
  const int*   idx1   = (const int*)d_in[15];
  const int*   mpi0   = (const int*)d_in[16];
  const int*   mdst0  = (const int*)d_in[17];
  const int*   mtgt0  = (const int*)d_in[18];
  const int*   mpi1   = (const int*)d_in[19];
  const int*   mdst1  = (const int*)d_in[20];
  const int*   mtgt1  = (const int*)d_in[21];

  float* ws      = (float*)d_ws;
  __half* tf16   = (__half*)(ws + OFF_TF16);
  float* finals  = ws + OFF_FINALS;
  float* acc     = ws + OFF_ACC;
  float* beta    = ws + OFF_BETA;
  __half* wc0    = (__half*)(ws + OFF_WC0);
  __half* wc1    = (__half*)(ws + OFF_WC1);
  float* bc0     = ws + OFF_BC0;
  float* bc1     = ws + OFF_BC1;
  __half* fc1h   = (__half*)(ws + OFF_FC1H);
  __half* P      = (__half*)(ws + OFF_P);
  int4*  sorted  = (int4*)(ws + OFF_SORTED);
  int*   counts  = (int*)(ws + OFF_COUNTS);
  int*   cntt    = (int*)(ws + OFF_CNTT);
  int*   curs    = (int*)(ws + OFF_CURS);
  int*   offs    = (int*)(ws + OFF_OFFS);
  __half* ft16o  = (__half*)(ws + OFF_FT16);
  __half* ft0h   = ft16o;
  __half* ft1h   = ft16o + (size_t)NG*512;

  k_wcat<<<289, 128, 0, stream>>>(r_vec, attn0, attn1, W0, b0, W1, b1, fc1_w,
                                  wc0, bc0, wc1, bc1, fc1h, finals, acc, beta);
  hipMemsetAsync(counts, 0, 2*16384*sizeof(int), stream);   // counts + cntt
  k_hist3<<<(2*NE + 2*NB + 255)/256, 256, 0, stream>>>(mdst0, mdst1, mtgt0, mtgt1,
                                                       counts, cntt);
  k_scan<<<1, 1024, 0, stream>>>(counts, offs, curs);
  k_scatter2<<<(2*NE + 255)/256, 256, 0, stream>>>(mpi0, mdst0, mpi1, mdst1,
                                                   offs, curs, sorted);

  k_tform<<<(NT0 + 63)/64 + (NT1 + 63)/64, 256, 0, stream>>>(
      feat0, idx0, feat1, idx1, wc0, bc0, wc1, bc1, tf16, P);

  k_seg<<<NG, 128, 0, stream>>>(tf16, P, sorted, offs, finals, ft16o);

  k_s1g<<<512, 256, 0, stream>>>(ft16o, cntt, fc1h, fc1_b, acc);
  k_beta<<<1, 64, 0, stream>>>(acc, fc2_w, beta);
  k_final<<<NB, 512, 0, stream>>>(ft0h, ft1h, mtgt0, mtgt1, beta, fc_w, fc_b,
                                  (float*)d_out);
}

// Round 13
// 215.202 us; speedup vs baseline: 1.2800x; 1.0481x over previous
//
#include <hip/hip_runtime.h>
#include <hip/hip_fp16.h>
#include <math.h>

#define NNODES 100000
#define NT0 60000
#define NT1 40000
#define FD0 128
#define FD1 64
#define HID 64
#define HEADS 8
#define OUTD 16
#define AVEC 128
#define NE 250000
#define NG 8192
#define NB 8192

typedef _Float16 half8v __attribute__((ext_vector_type(8)));
typedef float f32x4 __attribute__((ext_vector_type(4)));

// workspace layout (float offsets)
#define OFF_TF16    0ull          // 3,200,000
#define OFF_FINALS  3200000ull    // 512
#define OFF_ACC     3200512ull    // 256
#define OFF_BETA    3200768ull    // 256
#define OFF_WC0     3201024ull    // 7,168  (f16 [112][128])
#define OFF_WC1     3208192ull    // 3,584  (f16 [112][64])
#define OFF_BC0     3211776ull    // 128
#define OFF_BC1     3211904ull    // 128
#define OFF_FC1H    3212032ull    // 32,768 (f16 [128][512])
#define OFF_P       3244800ull    // 2,400,000 (f16 P[2][100000][24])
#define OFF_SORTED  5644800ull    // 2,000,000 (500,000 int4; byte off % 16 == 0)
#define OFF_COUNTS  7644800ull    // 16,384 ints
#define OFF_CNTT    7661184ull    // 16,384 ints (contiguous with COUNTS)
#define OFF_CURS    7677568ull    // 16,384 ints
#define OFF_OFFS    7693952ull    // 16,640 ints (16,385 used)
#define OFF_FT16    7710592ull    // 4,194,304 (f16 2*NG*512)
#define OFF_L       11904896ull   // 262,144 (f32 L[2][NG][16])
#define OFF_FCWH    12167040ull   // 4,096 (f16 [16][512])
// total = 12,171,136 floats = 48.7 MB

// ---- compute one rotation float2 for (pi, pair j) from r_vec ----
__device__ __forceinline__ float2 rot_pair(const float* r_vec, int pi, int j){
  const float2* rv = (const float2*)r_vec;
  int rel = pi >= 3 ? 1 : 0;
  float2 r = rv[rel*32 + j];
  float n = rsqrtf(r.x*r.x + r.y*r.y);
  r.x *= n; r.y *= n;
  float2 rf = make_float2(r.x, -r.y);           // conj
  int pos = pi - rel*3;
  if (pos == 2) return make_float2(1.f, 0.f);
  if (pos == 1) return rf;
  return make_float2(rf.x*r.x - rf.y*r.y, rf.x*r.y + rf.y*r.x);  // rf * r
}

// ---- wcat: Wcat rows + fc1h + prep + zero counts + fcwh, fully parallel ----
// grid 298 x 128: 0..111 wc0 rows, 112..223 wc1 rows, 224..287 fc1h,
// 288 prep (finals/acc/beta), 289..296 zero counts+cntt, 297 fc_w->fcwh
__global__ __launch_bounds__(128) void k_wcat(const float* __restrict__ r_vec,
     const float* __restrict__ attn0, const float* __restrict__ attn1,
     const float* __restrict__ W0v, const float* __restrict__ b0v,
     const float* __restrict__ W1v, const float* __restrict__ b1v,
     const float* __restrict__ fc1_w, const float* __restrict__ fc_w,
     __half* __restrict__ wc0, float* __restrict__ bc0,
     __half* __restrict__ wc1, float* __restrict__ bc1,
     __half* __restrict__ fc1h, __half* __restrict__ fcwh,
     int* __restrict__ counts,
     float* __restrict__ finals, float* __restrict__ acc, float* __restrict__ beta){
  int bid = blockIdx.x;
  int t = threadIdx.x;
  if (bid == 297){
    for (int i = t; i < OUTD*512; i += 128) fcwh[i] = __float2half(fc_w[i]);
    return;
  }
  if (bid >= 289){
    int base = (bid - 289)*4096;
    #pragma unroll
    for (int i = t; i < 4096; i += 128) counts[base + i] = 0;
    return;
  }
  if (bid == 288){
    if (t < 32){
      float2* F = (float2*)finals;
      #pragma unroll
      for (int pi = 0; pi < 6; ++pi) F[pi*32 + t] = rot_pair(r_vec, pi, t);
    }
    for (int q = t; q < 256; q += 128) acc[q] = 0.f;
    if (t < 2) beta[t] = 0.f;
    return;
  }
  if (bid >= 224){
    int base = (bid - 224)*1024;
    for (int i = t; i < 1024; i += 128)
      fc1h[base + i] = __float2half(fc1_w[base + i]);
    return;
  }
  int type = bid >= 112;
  int c = bid - type*112;
  int F = type ? FD1 : FD0;
  const float* W  = type ? W1v : W0v;
  const float* bv = type ? b1v : b0v;
  __half* wc = type ? wc1 : wc0;
  float* bc  = type ? bc1 : bc0;

  if (c < 64){
    for (int f = t; f < F; f += 128) wc[(size_t)c*F + f] = __float2half(W[(size_t)c*F + f]);
    if (t == 0) bc[c] = bv[c];
    return;
  }
  __shared__ float a[64];
  int cg = c - 64;          // 0..47
  int pi = cg >> 3, k = cg & 7;
  if (t < 32){
    float2 f = rot_pair(r_vec, pi, t);
    const float* at = (pi >= 3) ? attn1 : attn0;
    float a0 = at[k*64 + 2*t], a1 = at[k*64 + 2*t + 1];
    a[2*t]     = (f.x*a0 + f.y*a1) * (1.f/3.f);
    a[2*t + 1] = (f.x*a1 - f.y*a0) * (1.f/3.f);
  }
  __syncthreads();
  for (int f = t; f < F; f += 128){
    float s = 0.f;
    #pragma unroll 16
    for (int d = 0; d < 64; ++d) s += a[d] * W[(size_t)d*F + f];
    wc[(size_t)c*F + f] = __float2half(s);
  }
  if (t == 0){
    float s = 0.f;
    #pragma unroll 16
    for (int d = 0; d < 64; ++d) s += a[d] * bv[d];
    bc[c] = s;
  }
}

// ---- fused transform+P via MFMA; LDS-staged coalesced output ----
__global__ __launch_bounds__(256) void k_tform(const float* __restrict__ feat0,
      const int* __restrict__ idx0, const float* __restrict__ feat1,
      const int* __restrict__ idx1,
      const __half* __restrict__ wc0, const float* __restrict__ bc0,
      const __half* __restrict__ wc1, const float* __restrict__ bc1,
      __half* __restrict__ tf16, __half* __restrict__ P){
  const int nb0 = (NT0 + 63)/64;
  int bid = blockIdx.x;
  const float* feat; const int* idx; const __half* wc; const float* bc;
  int n_nodes, F, m0;
  if (bid < nb0){ feat=feat0; idx=idx0; wc=wc0; bc=bc0; n_nodes=NT0; F=FD0; m0=bid*64; }
  else { feat=feat1; idx=idx1; wc=wc1; bc=bc1; n_nodes=NT1; F=FD1; m0=(bid-nb0)*64; }
  __shared__ int idxs[64];
  __shared__ __half outs[64][120];   // [node][col], 240B row stride
  int t = threadIdx.x;
  if (t < 64){
    int gm = m0 + t; if (gm > n_nodes - 1) gm = n_nodes - 1;
    idxs[t] = idx[gm];
  }
  __syncthreads();
  int w = t >> 6, l = t & 63;
  int lr = l & 15, lk = l >> 4;
  int gr = m0 + w*16 + lr; if (gr > n_nodes - 1) gr = n_nodes - 1;
  const float* arow = feat + (size_t)gr*F;

  f32x4 acc7[7];
  #pragma unroll
  for (int ct = 0; ct < 7; ++ct) acc7[ct] = (f32x4){0.f,0.f,0.f,0.f};

  int nk = F >> 5;
  for (int kk = 0; kk < nk; ++kk){
    int koff = kk*32 + lk*8;
    float4 ua = *(const float4*)(arow + koff);
    float4 ub = *(const float4*)(arow + koff + 4);
    half8v a = {(_Float16)ua.x,(_Float16)ua.y,(_Float16)ua.z,(_Float16)ua.w,
                (_Float16)ub.x,(_Float16)ub.y,(_Float16)ub.z,(_Float16)ub.w};
    #pragma unroll
    for (int ct = 0; ct < 7; ++ct){
      half8v b = *(const half8v*)(wc + (size_t)(ct*16 + lr)*F + koff);
      acc7[ct] = __builtin_amdgcn_mfma_f32_16x16x32_f16(a, b, acc7[ct], 0, 0, 0);
    }
  }

  #pragma unroll
  for (int ct = 0; ct < 7; ++ct){
    int col = ct*16 + lr;
    float bvv = bc[col];
    #pragma unroll
    for (int r = 0; r < 4; ++r){
      int nl = w*16 + lk*4 + r;
      outs[nl][col] = __float2half(acc7[ct][r] + bvv);
    }
  }
  __syncthreads();
  #pragma unroll
  for (int u = t; u < 512; u += 256){
    int n = u >> 3, c = u & 7;
    if (m0 + n < n_nodes){
      uint4 v = *(uint4*)&outs[n][c*8];
      *(uint4*)&tf16[(size_t)idxs[n]*64 + c*8] = v;
    }
  }
  for (int u = t; u < 384; u += 256){
    int pp = u >= 192;
    int rr = u - pp*192;
    int n = rr / 3, c = rr - n*3;
    if (m0 + n < n_nodes){
      uint4 v = *(uint4*)&outs[n][64 + pp*24 + c*8];
      *(uint4*)&P[(size_t)pp*2400000 + (size_t)idxs[n]*24 + c*8] = v;
    }
  }
}

// ---- histograms: dst (both p) + tgt (both p) ----
__global__ void k_hist3(const int* __restrict__ d0, const int* __restrict__ d1,
                        const int* __restrict__ t0, const int* __restrict__ t1,
                        int* __restrict__ counts, int* __restrict__ cntt){
  int e = blockIdx.x*blockDim.x + threadIdx.x;
  if (e < NE) atomicAdd(&counts[d0[e]], 1);
  else if (e < 2*NE) atomicAdd(&counts[NG + d1[e-NE]], 1);
  else if (e < 2*NE + NB) atomicAdd(&cntt[t0[e-2*NE]], 1);
  else if (e < 2*NE + 2*NB) atomicAdd(&cntt[NG + t1[e-2*NE-NB]], 1);
}

// ---- exclusive scan over 16384 counts; also zero cursors ----
__global__ __launch_bounds__(1024) void k_scan(const int* __restrict__ counts,
                                               int* __restrict__ offs,
                                               int* __restrict__ curs){
  __shared__ int lds[1024];
  int t = threadIdx.x;
  int base = t*16;
  int v[16]; int sum = 0;
  #pragma unroll
  for (int i = 0; i < 16; ++i){ v[i] = counts[base+i]; sum += v[i]; }
  lds[t] = sum;
  __syncthreads();
  for (int off = 1; off < 1024; off <<= 1){
    int x = (t >= off) ? lds[t-off] : 0;
    __syncthreads();
    lds[t] += x;
    __syncthreads();
  }
  int excl = lds[t] - sum;
  #pragma unroll
  for (int i = 0; i < 16; ++i){ offs[base+i] = excl; excl += v[i]; curs[base+i] = 0; }
  if (t == 1023) offs[2*NG] = excl;
}

// ---- scatter both metapaths' edges into dst-sorted order ----
__global__ void k_scatter2(const int* __restrict__ m0, const int* __restrict__ d0,
                           const int* __restrict__ m1, const int* __restrict__ d1,
                           const int* __restrict__ offs, int* __restrict__ curs,
                           int4* __restrict__ sorted){
  int e = blockIdx.x*blockDim.x + threadIdx.x;
  if (e >= 2*NE) return;
  const int* mp; int d;
  if (e < NE){ mp = m0 + (size_t)e*3; d = d0[e]; }
  else { mp = m1 + (size_t)(e-NE)*3; d = NG + d1[e-NE]; }
  int pos = offs[d] + atomicAdd(&curs[d], 1);
  sorted[pos] = make_int4(mp[0], mp[1], mp[2], 0);
}

// ---- fused per-segment softmax-agg; 2 independent waves per block ----
__global__ __launch_bounds__(128) void k_seg(const __half* __restrict__ tf16,
                                             const __half* __restrict__ P,
                                             const int4* __restrict__ sorted,
                                             const int* __restrict__ offs,
                                             const float* __restrict__ finals,
                                             __half* __restrict__ ft16o){
  __shared__ int4 ndb[2][64];
  __shared__ float wb[2][64][8];
  int wv = threadIdx.x >> 6;
  int seg = blockIdx.x*2 + wv;           // grid NG blocks -> 2*NG segments
  int p = seg >> 13;
  int lane = threadIdx.x & 63;
  int hw = lane >> 5, j = lane & 31;
  int start = offs[seg], end = offs[seg+1];
  __half2* ftw = (__half2*)(ft16o + (size_t)seg*512);
  if (start == end){
    #pragma unroll
    for (int kk = 0; kk < 4; ++kk) ftw[(hw*4+kk)*32 + j] = __floats2half2_rn(0.f, 0.f);
    return;
  }
  const float2* F2 = (const float2*)(finals + p*192);
  float2 f0 = F2[j], f1 = F2[32 + j];
  const __half2* tfh = (const __half2*)tf16;
  const __half* Pp = P + (size_t)p*2400000;
  int4* nb = ndb[wv];
  float (*wbp)[8] = wb[wv];

  float sA[8], ur[8], ui[8];
  #pragma unroll
  for (int k = 0; k < 8; ++k){ sA[k] = 0.f; ur[k] = 0.f; ui[k] = 0.f; }

  for (int c = start; c < end; c += 64){
    int n = end - c; if (n > 64) n = 64;
    // ---- phase A: logits + s accumulation (lane-per-edge) ----
    if (lane < n){
      int4 nd = sorted[c + lane];
      nb[lane] = nd;
      float4 rA = *(const float4*)(Pp + (size_t)nd.x*24);
      float4 rB = *(const float4*)(Pp + (size_t)nd.y*24 + 8);
      float4 rC = *(const float4*)(Pp + (size_t)nd.z*24 + 16);
      const __half2* ha = (const __half2*)&rA;
      const __half2* hb = (const __half2*)&rB;
      const __half2* hc = (const __half2*)&rC;
      float w[8];
      #pragma unroll
      for (int m = 0; m < 4; ++m){
        float2 va = __half22float2(ha[m]);
        float2 vb = __half22float2(hb[m]);
        float2 vc = __half22float2(hc[m]);
        float x0 = va.x + vb.x + vc.x;
        float x1 = va.y + vb.y + vc.y;
        x0 = x0 > 0.f ? x0 : 0.01f*x0;
        x1 = x1 > 0.f ? x1 : 0.01f*x1;
        w[2*m]   = __expf(x0);
        w[2*m+1] = __expf(x1);
      }
      #pragma unroll
      for (int k = 0; k < 8; ++k) sA[k] += w[k];
      *(float4*)&wbp[lane][0] = make_float4(w[0], w[1], w[2], w[3]);
      *(float4*)&wbp[lane][4] = make_float4(w[4], w[5], w[6], w[7]);
    }
    // wave-internal LDS sync (no cross-wave barrier: trip counts differ)
    asm volatile("s_waitcnt lgkmcnt(0)" ::: "memory");
    __builtin_amdgcn_sched_barrier(0);
    // ---- phase B: weighted aggregation (half-wave per edge) ----
    int cend = c + n;
    #pragma unroll 2
    for (int i = c + hw; i < cend; i += 2){
      int e = i - c;
      int4 nd = nb[e];
      float4 wlo = *(const float4*)&wbp[e][0];
      float4 whi = *(const float4*)&wbp[e][4];
      float2 v0 = __half22float2(tfh[(size_t)nd.x*32 + j]);
      float2 v1 = __half22float2(tfh[(size_t)nd.y*32 + j]);
      float2 v2 = __half22float2(tfh[(size_t)nd.z*32 + j]);
      float hre = (v0.x*f0.x - v0.y*f0.y) + (v1.x*f1.x - v1.y*f1.y) + v2.x;
      float him = (v0.x*f0.y + v0.y*f0.x) + (v1.x*f1.y + v1.y*f1.x) + v2.y;
      ur[0] += wlo.x*hre; ui[0] += wlo.x*him;
      ur[1] += wlo.y*hre; ui[1] += wlo.y*him;
      ur[2] += wlo.z*hre; ui[2] += wlo.z*him;
      ur[3] += wlo.w*hre; ui[3] += wlo.w*him;
      ur[4] += whi.x*hre; ui[4] += whi.x*him;
      ur[5] += whi.y*hre; ui[5] += whi.y*him;
      ur[6] += whi.z*hre; ui[6] += whi.z*him;
      ur[7] += whi.w*hre; ui[7] += whi.w*him;
    }
    asm volatile("s_waitcnt lgkmcnt(0)" ::: "memory");
    __builtin_amdgcn_sched_barrier(0);
  }
  #pragma unroll
  for (int k = 0; k < 8; ++k){
    ur[k] += __shfl_xor(ur[k], 32);
    ui[k] += __shfl_xor(ui[k], 32);
    float v = sA[k];
    #pragma unroll
    for (int mask = 1; mask < 64; mask <<= 1) v += __shfl_xor(v, mask);
    sA[k] = v;
  }
  #pragma unroll
  for (int kk = 0; kk < 4; ++kk){
    int k = hw*4 + kk;
    float inv = 1.f / (3.f * sA[k]);
    float re = ur[k]*inv, im = ui[k]*inv;
    re = re > 0.f ? re : expm1f(re);    // elu fused
    im = im > 0.f ? im : expm1f(im);
    ftw[k*32 + j] = __floats2half2_rn(re, im);
  }
}

// ---- s1 via MFMA + fused output-head GEMM L = elu(ft) @ fc_w.T ----
__global__ __launch_bounds__(256) void k_s1g(const __half* __restrict__ ft16o,
                                             const int* __restrict__ cntt,
                                             const __half* __restrict__ fc1h,
                                             const float* __restrict__ fc1_b,
                                             const __half* __restrict__ fcwh,
                                             float* __restrict__ Lb,
                                             float* __restrict__ acc_p){
  int bid = blockIdx.x;
  int p  = bid >> 8;
  int rb = bid & 255;
  int t = threadIdx.x;
  int w = t >> 6, l = t & 63;
  int rowbase = rb*32 + (w & 1)*16;
  int colbase = (w >> 1)*64;
  int lr = l & 15, lk = l >> 4;
  bool doL = (w >> 1) == 0;   // waves 0,1 also compute the 16-col L tile

  const half8v* Ab = (const half8v*)(ft16o + ((size_t)p*NG + rowbase)*512);
  f32x4 acc[4] = {{0.f,0.f,0.f,0.f},{0.f,0.f,0.f,0.f},
                  {0.f,0.f,0.f,0.f},{0.f,0.f,0.f,0.f}};
  f32x4 accL = {0.f,0.f,0.f,0.f};

  #pragma unroll 4
  for (int kk = 0; kk < 16; ++kk){
    half8v a = Ab[(size_t)lr*64 + kk*4 + lk];
    #pragma unroll
    for (int ct = 0; ct < 4; ++ct){
      const half8v* Bb = (const half8v*)(fc1h + (size_t)(colbase + ct*16 + lr)*512);
      half8v b = Bb[kk*4 + lk];
      acc[ct] = __builtin_amdgcn_mfma_f32_16x16x32_f16(a, b, acc[ct], 0, 0, 0);
    }
    if (doL){
      half8v b = *(const half8v*)(fcwh + (size_t)lr*512 + kk*32 + lk*8);
      accL = __builtin_amdgcn_mfma_f32_16x16x32_f16(a, b, accL, 0, 0, 0);
    }
  }

  float cf[4];
  #pragma unroll
  for (int r = 0; r < 4; ++r)
    cf[r] = (float)cntt[p*NG + rowbase + lk*4 + r];
  #pragma unroll
  for (int ct = 0; ct < 4; ++ct){
    int col = colbase + ct*16 + lr;
    float bv = fc1_b[col];
    float sv = 0.f;
    #pragma unroll
    for (int r = 0; r < 4; ++r)
      sv += cf[r] * tanhf(acc[ct][r] + bv);
    sv += __shfl_xor(sv, 16);
    sv += __shfl_xor(sv, 32);
    if (l < 16) atomicAdd(&acc_p[p*128 + col], sv);
  }
  if (doL){
    #pragma unroll
    for (int r = 0; r < 4; ++r)
      Lb[((size_t)p*NG + rowbase + lk*4 + r)*16 + lr] = accL[r];
  }
}

// ---- beta softmax over 2 metapaths ----
__global__ void k_beta(const float* __restrict__ acc, const float* __restrict__ fc2_w,
                       float* __restrict__ beta){
  int t = threadIdx.x;  // 64
  float s0 = acc[t]*fc2_w[t] + acc[t+64]*fc2_w[t+64];
  float s1 = acc[128+t]*fc2_w[t] + acc[192+t]*fc2_w[t+64];
  #pragma unroll
  for (int mask = 1; mask < 64; mask <<= 1){
    s0 += __shfl_xor(s0, mask, 64);
    s1 += __shfl_xor(s1, mask, 64);
  }
  if (t == 0){
    float z0 = s0 / (float)NB, z1 = s1 / (float)NB;
    float mz = fmaxf(z0, z1);
    float e0 = expf(z0 - mz), e1 = expf(z1 - mz);
    float inv = 1.f / (e0 + e1);
    beta[0] = e0*inv; beta[1] = e1*inv;
  }
}

// ---- hagg write + logits gather (all heavy math pre-done) ----
__global__ void k_final(const __half* __restrict__ ft0, const __half* __restrict__ ft1,
                        const int* __restrict__ tgt0, const int* __restrict__ tgt1,
                        const float* __restrict__ beta, const float* __restrict__ Lb,
                        const float* __restrict__ fc_b, float* __restrict__ d_out){
  int b = blockIdx.x, t = threadIdx.x;  // 512 threads
  float b0 = beta[0], b1 = beta[1];
  int g0 = tgt0[b], g1 = tgt1[b];
  float v0 = __half2float(ft0[(size_t)g0*512 + t]);
  float v1 = __half2float(ft1[(size_t)g1*512 + t]);
  d_out[(size_t)NB*OUTD + (size_t)b*512 + t] = b0*v0 + b1*v1;
  if (t < OUTD){
    float lv = b0*Lb[(size_t)g0*16 + t] + b1*Lb[((size_t)NG + g1)*16 + t] + fc_b[t];
    d_out[(size_t)b*OUTD + t] = lv;
  }
}

extern "C" void kernel_launch(void* const* d_in, const int* in_sizes, int n_in,
                              void* d_out, int out_size, void* d_ws, size_t ws_size,
                              hipStream_t stream){
  const float* feat0  = (const float*)d_in[0];
  const float* feat1  = (const float*)d_in[1];
  const float* W0     = (const float*)d_in[2];
  const float* b0     = (const float*)d_in[3];
  const float* W1     = (const float*)d_in[4];
  const float* b1     = (const float*)d_in[5];
  const float* r_vec  = (const float*)d_in[6];
  const float* attn0  = (const float*)d_in[7];
  const float* attn1  = (const float*)d_in[8];
  const float* fc1_w  = (const float*)d_in[9];
  const float* fc1_b  = (const float*)d_in[10];
  const float* fc2_w  = (const float*)d_in[11];
  const float* fc_w   = (const float*)d_in[12];
  const float* fc_b   = (const float*)d_in[13];
  const int*   idx0   = (const int*)d_in[14];
  const int*   idx1   = (const int*)d_in[15];
  const int*   mpi0   = (const int*)d_in[16];
  const int*   mdst0  = (const int*)d_in[17];
  const int*   mtgt0  = (const int*)d_in[18];
  const int*   mpi1   = (const int*)d_in[19];
  const int*   mdst1  = (const int*)d_in[20];
  const int*   mtgt1  = (const int*)d_in[21];

  float* ws      = (float*)d_ws;
  __half* tf16   = (__half*)(ws + OFF_TF16);
  float* finals  = ws + OFF_FINALS;
  float* acc     = ws + OFF_ACC;
  float* beta    = ws + OFF_BETA;
  __half* wc0    = (__half*)(ws + OFF_WC0);
  __half* wc1    = (__half*)(ws + OFF_WC1);
  float* bc0     = ws + OFF_BC0;
  float* bc1     = ws + OFF_BC1;
  __half* fc1h   = (__half*)(ws + OFF_FC1H);
  __half* P      = (__half*)(ws + OFF_P);
  int4*  sorted  = (int4*)(ws + OFF_SORTED);
  int*   counts  = (int*)(ws + OFF_COUNTS);
  int*   cntt    = (int*)(ws + OFF_CNTT);
  int*   curs    = (int*)(ws + OFF_CURS);
  int*   offs    = (int*)(ws + OFF_OFFS);
  __half* ft16o  = (__half*)(ws + OFF_FT16);
  __half* ft0h   = ft16o;
  __half* ft1h   = ft16o + (size_t)NG*512;
  float* Lb      = ws + OFF_L;
  __half* fcwh   = (__half*)(ws + OFF_FCWH);

  k_wcat<<<298, 128, 0, stream>>>(r_vec, attn0, attn1, W0, b0, W1, b1, fc1_w, fc_w,
                                  wc0, bc0, wc1, bc1, fc1h, fcwh, counts,
                                  finals, acc, beta);
  k_hist3<<<(2*NE + 2*NB + 255)/256, 256, 0, stream>>>(mdst0, mdst1, mtgt0, mtgt1,
                                                       counts, cntt);
  k_scan<<<1, 1024, 0, stream>>>(counts, offs, curs);
  k_scatter2<<<(2*NE + 255)/256, 256, 0, stream>>>(mpi0, mdst0, mpi1, mdst1,
                                                   offs, curs, sorted);

  k_tform<<<(NT0 + 63)/64 + (NT1 + 63)/64, 256, 0, stream>>>(
      feat0, idx0, feat1, idx1, wc0, bc0, wc1, bc1, tf16, P);

  k_seg<<<NG, 128, 0, stream>>>(tf16, P, sorted, offs, finals, ft16o);

  k_s1g<<<512, 256, 0, stream>>>(ft16o, cntt, fc1h, fc1_b, fcwh, Lb, acc);
  k_beta<<<1, 64, 0, stream>>>(acc, fc2_w, beta);
  k_final<<<NB, 512, 0, stream>>>(ft0h, ft1h, mtgt0, mtgt1, beta, Lb, fc_b,
                                  (float*)d_out);
}

// Round 15
// 210.871 us; speedup vs baseline: 1.3063x; 1.0205x over previous
//
#include <hip/hip_runtime.h>
#include <hip/hip_fp16.h>
#include <math.h>

#define NNODES 100000
#define NT0 60000
#define NT1 40000
#define FD0 128
#define FD1 64
#define HID 64
#define HEADS 8
#define OUTD 16
#define AVEC 128
#define NE 250000
#define NG 8192
#define NB 8192

typedef _Float16 half8v __attribute__((ext_vector_type(8)));
typedef float f32x4 __attribute__((ext_vector_type(4)));

// workspace layout (float offsets)
#define OFF_TF16    0ull          // 3,200,000
#define OFF_FINALS  3200000ull    // 512
#define OFF_ACC     3200512ull    // 256
#define OFF_BETA    3200768ull    // 256 (unused)
#define OFF_WC0     3201024ull    // 7,168  (f16 [112][128])
#define OFF_WC1     3208192ull    // 3,584  (f16 [112][64])
#define OFF_BC0     3211776ull    // 128
#define OFF_BC1     3211904ull    // 128
#define OFF_FC1H    3212032ull    // 32,768 (f16 [128][512])
#define OFF_P       3244800ull    // 2,400,000 (f16 P[2][100000][24])
#define OFF_SORTED  5644800ull    // 2,000,000 (500,000 int4; byte off % 16 == 0)
#define OFF_COUNTS  7644800ull    // 16,384 ints
#define OFF_CNTT    7661184ull    // 16,384 ints (contiguous with COUNTS)
#define OFF_CURS    7677568ull    // 16,384 ints
#define OFF_OFFS    7693952ull    // 16,640 ints (16,385 used)
#define OFF_FT16    7710592ull    // 4,194,304 (f16 2*NG*512)
#define OFF_L       11904896ull   // 262,144 (f32 L[2][NG][16])
#define OFF_FCWH    12167040ull   // 4,096 (f16 [16][512])
// total = 12,171,136 floats = 48.7 MB

#define NB_TF0 ((NT0 + 63)/64)
#define NB_TF1 ((NT1 + 63)/64)
#define NB_TF  (NB_TF0 + NB_TF1)             // 1563
#define NB_SC  ((2*NE + 255)/256)            // 1954

// ---- compute one rotation float2 for (pi, pair j) from r_vec ----
__device__ __forceinline__ float2 rot_pair(const float* r_vec, int pi, int j){
  const float2* rv = (const float2*)r_vec;
  int rel = pi >= 3 ? 1 : 0;
  float2 r = rv[rel*32 + j];
  float n = rsqrtf(r.x*r.x + r.y*r.y);
  r.x *= n; r.y *= n;
  float2 rf = make_float2(r.x, -r.y);           // conj
  int pos = pi - rel*3;
  if (pos == 2) return make_float2(1.f, 0.f);
  if (pos == 1) return rf;
  return make_float2(rf.x*r.x - rf.y*r.y, rf.x*r.y + rf.y*r.x);  // rf * r
}

// ---- wcat: Wcat rows + fc1h + prep + zero counts + fcwh ----
// grid 298 x 128 (zeroing blocks 289..296 are ordered BEFORE k_hist3 by the
// kernel boundary — do NOT merge histograms into this grid, dispatch order
// within a grid is undefined and races with the zeroing [R14 lesson])
__global__ __launch_bounds__(128) void k_wcat(const float* __restrict__ r_vec,
     const float* __restrict__ attn0, const float* __restrict__ attn1,
     const float* __restrict__ W0v, const float* __restrict__ b0v,
     const float* __restrict__ W1v, const float* __restrict__ b1v,
     const float* __restrict__ fc1_w, const float* __restrict__ fc_w,
     __half* __restrict__ wc0, float* __restrict__ bc0,
     __half* __restrict__ wc1, float* __restrict__ bc1,
     __half* __restrict__ fc1h, __half* __restrict__ fcwh,
     int* __restrict__ counts,
     float* __restrict__ finals, float* __restrict__ acc){
  int bid = blockIdx.x;
  int t = threadIdx.x;
  if (bid == 297){
    for (int i = t; i < OUTD*512; i += 128) fcwh[i] = __float2half(fc_w[i]);
    return;
  }
  if (bid >= 289){
    int base = (bid - 289)*4096;
    #pragma unroll
    for (int i = t; i < 4096; i += 128) counts[base + i] = 0;
    return;
  }
  if (bid == 288){
    if (t < 32){
      float2* F = (float2*)finals;
      #pragma unroll
      for (int pi = 0; pi < 6; ++pi) F[pi*32 + t] = rot_pair(r_vec, pi, t);
    }
    for (int q = t; q < 256; q += 128) acc[q] = 0.f;
    return;
  }
  if (bid >= 224){
    int base = (bid - 224)*1024;
    for (int i = t; i < 1024; i += 128)
      fc1h[base + i] = __float2half(fc1_w[base + i]);
    return;
  }
  int type = bid >= 112;
  int c = bid - type*112;
  int F = type ? FD1 : FD0;
  const float* W  = type ? W1v : W0v;
  const float* bv = type ? b1v : b0v;
  __half* wc = type ? wc1 : wc0;
  float* bc  = type ? bc1 : bc0;

  if (c < 64){
    for (int f = t; f < F; f += 128) wc[(size_t)c*F + f] = __float2half(W[(size_t)c*F + f]);
    if (t == 0) bc[c] = bv[c];
    return;
  }
  __shared__ float a[64];
  int cg = c - 64;          // 0..47
  int pi = cg >> 3, k = cg & 7;
  if (t < 32){
    float2 f = rot_pair(r_vec, pi, t);
    const float* at = (pi >= 3) ? attn1 : attn0;
    float a0 = at[k*64 + 2*t], a1 = at[k*64 + 2*t + 1];
    a[2*t]     = (f.x*a0 + f.y*a1) * (1.f/3.f);
    a[2*t + 1] = (f.x*a1 - f.y*a0) * (1.f/3.f);
  }
  __syncthreads();
  for (int f = t; f < F; f += 128){
    float s = 0.f;
    #pragma unroll 16
    for (int d = 0; d < 64; ++d) s += a[d] * W[(size_t)d*F + f];
    wc[(size_t)c*F + f] = __float2half(s);
  }
  if (t == 0){
    float s = 0.f;
    #pragma unroll 16
    for (int d = 0; d < 64; ++d) s += a[d] * bv[d];
    bc[c] = s;
  }
}

// ---- histograms: dst (both p) + tgt (both p) ----
__global__ void k_hist3(const int* __restrict__ d0, const int* __restrict__ d1,
                        const int* __restrict__ t0, const int* __restrict__ t1,
                        int* __restrict__ counts, int* __restrict__ cntt){
  int e = blockIdx.x*blockDim.x + threadIdx.x;
  if (e < NE) atomicAdd(&counts[d0[e]], 1);
  else if (e < 2*NE) atomicAdd(&counts[NG + d1[e-NE]], 1);
  else if (e < 2*NE + NB) atomicAdd(&cntt[t0[e-2*NE]], 1);
  else if (e < 2*NE + 2*NB) atomicAdd(&cntt[NG + t1[e-2*NE-NB]], 1);
}

// ---- exclusive scan over 16384 counts; also zero cursors ----
__global__ __launch_bounds__(1024) void k_scan(const int* __restrict__ counts,
                                               int* __restrict__ offs,
                                               int* __restrict__ curs){
  __shared__ int lds[1024];
  int t = threadIdx.x;
  int base = t*16;
  int v[16]; int sum = 0;
  #pragma unroll
  for (int i = 0; i < 16; ++i){ v[i] = counts[base+i]; sum += v[i]; }
  lds[t] = sum;
  __syncthreads();
  for (int off = 1; off < 1024; off <<= 1){
    int x = (t >= off) ? lds[t-off] : 0;
    __syncthreads();
    lds[t] += x;
    __syncthreads();
  }
  int excl = lds[t] - sum;
  #pragma unroll
  for (int i = 0; i < 16; ++i){ offs[base+i] = excl; excl += v[i]; curs[base+i] = 0; }
  if (t == 1023) offs[2*NG] = excl;
}

// ---- mid: tform (MFMA, blocks 0..NB_TF-1) + scatter (blocks NB_TF..) ----
__global__ __launch_bounds__(256) void k_mid(const float* __restrict__ feat0,
      const int* __restrict__ idx0, const float* __restrict__ feat1,
      const int* __restrict__ idx1,
      const __half* __restrict__ wc0, const float* __restrict__ bc0,
      const __half* __restrict__ wc1, const float* __restrict__ bc1,
      const int* __restrict__ m0, const int* __restrict__ d0,
      const int* __restrict__ m1, const int* __restrict__ d1,
      const int* __restrict__ offs, int* __restrict__ curs,
      int4* __restrict__ sorted,
      __half* __restrict__ tf16, __half* __restrict__ P){
  int bid = blockIdx.x;
  int t = threadIdx.x;
  if (bid >= NB_TF){
    // ---- scatter ----
    int e = (bid - NB_TF)*256 + t;
    if (e >= 2*NE) return;
    const int* mp; int d;
    if (e < NE){ mp = m0 + (size_t)e*3; d = d0[e]; }
    else { mp = m1 + (size_t)(e-NE)*3; d = NG + d1[e-NE]; }
    int pos = offs[d] + atomicAdd(&curs[d], 1);
    sorted[pos] = make_int4(mp[0], mp[1], mp[2], 0);
    return;
  }
  // ---- tform ----
  const float* feat; const int* idx; const __half* wc; const float* bc;
  int n_nodes, F, m0b;
  if (bid < NB_TF0){ feat=feat0; idx=idx0; wc=wc0; bc=bc0; n_nodes=NT0; F=FD0; m0b=bid*64; }
  else { feat=feat1; idx=idx1; wc=wc1; bc=bc1; n_nodes=NT1; F=FD1; m0b=(bid-NB_TF0)*64; }
  __shared__ int idxs[64];
  __shared__ __half outs[64][120];   // [node][col], 240B row stride
  if (t < 64){
    int gm = m0b + t; if (gm > n_nodes - 1) gm = n_nodes - 1;
    idxs[t] = idx[gm];
  }
  __syncthreads();
  int w = t >> 6, l = t & 63;
  int lr = l & 15, lk = l >> 4;
  int gr = m0b + w*16 + lr; if (gr > n_nodes - 1) gr = n_nodes - 1;
  const float* arow = feat + (size_t)gr*F;

  f32x4 acc7[7];
  #pragma unroll
  for (int ct = 0; ct < 7; ++ct) acc7[ct] = (f32x4){0.f,0.f,0.f,0.f};

  int nk = F >> 5;
  for (int kk = 0; kk < nk; ++kk){
    int koff = kk*32 + lk*8;
    float4 ua = *(const float4*)(arow + koff);
    float4 ub = *(const float4*)(arow + koff + 4);
    half8v a = {(_Float16)ua.x,(_Float16)ua.y,(_Float16)ua.z,(_Float16)ua.w,
                (_Float16)ub.x,(_Float16)ub.y,(_Float16)ub.z,(_Float16)ub.w};
    #pragma unroll
    for (int ct = 0; ct < 7; ++ct){
      half8v b = *(const half8v*)(wc + (size_t)(ct*16 + lr)*F + koff);
      acc7[ct] = __builtin_amdgcn_mfma_f32_16x16x32_f16(a, b, acc7[ct], 0, 0, 0);
    }
  }

  #pragma unroll
  for (int ct = 0; ct < 7; ++ct){
    int col = ct*16 + lr;
    float bvv = bc[col];
    #pragma unroll
    for (int r = 0; r < 4; ++r){
      int nl = w*16 + lk*4 + r;
      outs[nl][col] = __float2half(acc7[ct][r] + bvv);
    }
  }
  __syncthreads();
  #pragma unroll
  for (int u = t; u < 512; u += 256){
    int n = u >> 3, c = u & 7;
    if (m0b + n < n_nodes){
      uint4 v = *(uint4*)&outs[n][c*8];
      *(uint4*)&tf16[(size_t)idxs[n]*64 + c*8] = v;
    }
  }
  for (int u = t; u < 384; u += 256){
    int pp = u >= 192;
    int rr = u - pp*192;
    int n = rr / 3, c = rr - n*3;
    if (m0b + n < n_nodes){
      uint4 v = *(uint4*)&outs[n][64 + pp*24 + c*8];
      *(uint4*)&P[(size_t)pp*2400000 + (size_t)idxs[n]*24 + c*8] = v;
    }
  }
}

// ---- fused per-segment softmax-agg; 2 independent waves per block ----
__global__ __launch_bounds__(128) void k_seg(const __half* __restrict__ tf16,
                                             const __half* __restrict__ P,
                                             const int4* __restrict__ sorted,
                                             const int* __restrict__ offs,
                                             const float* __restrict__ finals,
                                             __half* __restrict__ ft16o){
  __shared__ int4 ndb[2][64];
  __shared__ float wb[2][64][8];
  int wv = threadIdx.x >> 6;
  int seg = blockIdx.x*2 + wv;           // grid NG blocks -> 2*NG segments
  int p = seg >> 13;
  int lane = threadIdx.x & 63;
  int hw = lane >> 5, j = lane & 31;
  int start = offs[seg], end = offs[seg+1];
  __half2* ftw = (__half2*)(ft16o + (size_t)seg*512);
  if (start == end){
    #pragma unroll
    for (int kk = 0; kk < 4; ++kk) ftw[(hw*4+kk)*32 + j] = __floats2half2_rn(0.f, 0.f);
    return;
  }
  const float2* F2 = (const float2*)(finals + p*192);
  float2 f0 = F2[j], f1 = F2[32 + j];
  const __half2* tfh = (const __half2*)tf16;
  const __half* Pp = P + (size_t)p*2400000;
  int4* nb = ndb[wv];
  float (*wbp)[8] = wb[wv];

  float sA[8], ur[8], ui[8];
  #pragma unroll
  for (int k = 0; k < 8; ++k){ sA[k] = 0.f; ur[k] = 0.f; ui[k] = 0.f; }

  for (int c = start; c < end; c += 64){
    int n = end - c; if (n > 64) n = 64;
    // ---- phase A: logits + s accumulation (lane-per-edge) ----
    if (lane < n){
      int4 nd = sorted[c + lane];
      nb[lane] = nd;
      float4 rA = *(const float4*)(Pp + (size_t)nd.x*24);
      float4 rB = *(const float4*)(Pp + (size_t)nd.y*24 + 8);
      float4 rC = *(const float4*)(Pp + (size_t)nd.z*24 + 16);
      const __half2* ha = (const __half2*)&rA;
      const __half2* hb = (const __half2*)&rB;
      const __half2* hc = (const __half2*)&rC;
      float w[8];
      #pragma unroll
      for (int m = 0; m < 4; ++m){
        float2 va = __half22float2(ha[m]);
        float2 vb = __half22float2(hb[m]);
        float2 vc = __half22float2(hc[m]);
        float x0 = va.x + vb.x + vc.x;
        float x1 = va.y + vb.y + vc.y;
        x0 = x0 > 0.f ? x0 : 0.01f*x0;
        x1 = x1 > 0.f ? x1 : 0.01f*x1;
        w[2*m]   = __expf(x0);
        w[2*m+1] = __expf(x1);
      }
      #pragma unroll
      for (int k = 0; k < 8; ++k) sA[k] += w[k];
      *(float4*)&wbp[lane][0] = make_float4(w[0], w[1], w[2], w[3]);
      *(float4*)&wbp[lane][4] = make_float4(w[4], w[5], w[6], w[7]);
    }
    // wave-internal LDS sync (no cross-wave barrier: trip counts differ)
    asm volatile("s_waitcnt lgkmcnt(0)" ::: "memory");
    __builtin_amdgcn_sched_barrier(0);
    // ---- phase B: weighted aggregation (half-wave per edge) ----
    int cend = c + n;
    #pragma unroll 2
    for (int i = c + hw; i < cend; i += 2){
      int e = i - c;
      int4 nd = nb[e];
      float4 wlo = *(const float4*)&wbp[e][0];
      float4 whi = *(const float4*)&wbp[e][4];
      float2 v0 = __half22float2(tfh[(size_t)nd.x*32 + j]);
      float2 v1 = __half22float2(tfh[(size_t)nd.y*32 + j]);
      float2 v2 = __half22float2(tfh[(size_t)nd.z*32 + j]);
      float hre = (v0.x*f0.x - v0.y*f0.y) + (v1.x*f1.x - v1.y*f1.y) + v2.x;
      float him = (v0.x*f0.y + v0.y*f0.x) + (v1.x*f1.y + v1.y*f1.x) + v2.y;
      ur[0] += wlo.x*hre; ui[0] += wlo.x*him;
      ur[1] += wlo.y*hre; ui[1] += wlo.y*him;
      ur[2] += wlo.z*hre; ui[2] += wlo.z*him;
      ur[3] += wlo.w*hre; ui[3] += wlo.w*him;
      ur[4] += whi.x*hre; ui[4] += whi.x*him;
      ur[5] += whi.y*hre; ui[5] += whi.y*him;
      ur[6] += whi.z*hre; ui[6] += whi.z*him;
      ur[7] += whi.w*hre; ui[7] += whi.w*him;
    }
    asm volatile("s_waitcnt lgkmcnt(0)" ::: "memory");
    __builtin_amdgcn_sched_barrier(0);
  }
  #pragma unroll
  for (int k = 0; k < 8; ++k){
    ur[k] += __shfl_xor(ur[k], 32);
    ui[k] += __shfl_xor(ui[k], 32);
    float v = sA[k];
    #pragma unroll
    for (int mask = 1; mask < 64; mask <<= 1) v += __shfl_xor(v, mask);
    sA[k] = v;
  }
  #pragma unroll
  for (int kk = 0; kk < 4; ++kk){
    int k = hw*4 + kk;
    float inv = 1.f / (3.f * sA[k]);
    float re = ur[k]*inv, im = ui[k]*inv;
    re = re > 0.f ? re : expm1f(re);    // elu fused
    im = im > 0.f ? im : expm1f(im);
    ftw[k*32 + j] = __floats2half2_rn(re, im);
  }
}

// ---- s1 via MFMA + fused output-head GEMM L = elu(ft) @ fc_w.T ----
__global__ __launch_bounds__(256) void k_s1g(const __half* __restrict__ ft16o,
                                             const int* __restrict__ cntt,
                                             const __half* __restrict__ fc1h,
                                             const float* __restrict__ fc1_b,
                                             const __half* __restrict__ fcwh,
                                             float* __restrict__ Lb,
                                             float* __restrict__ acc_p){
  int bid = blockIdx.x;
  int p  = bid >> 8;
  int rb = bid & 255;
  int t = threadIdx.x;
  int w = t >> 6, l = t & 63;
  int rowbase = rb*32 + (w & 1)*16;
  int colbase = (w >> 1)*64;
  int lr = l & 15, lk = l >> 4;
  bool doL = (w >> 1) == 0;   // waves 0,1 also compute the 16-col L tile

  const half8v* Ab = (const half8v*)(ft16o + ((size_t)p*NG + rowbase)*512);
  f32x4 acc[4] = {{0.f,0.f,0.f,0.f},{0.f,0.f,0.f,0.f},
                  {0.f,0.f,0.f,0.f},{0.f,0.f,0.f,0.f}};
  f32x4 accL = {0.f,0.f,0.f,0.f};

  #pragma unroll 4
  for (int kk = 0; kk < 16; ++kk){
    half8v a = Ab[(size_t)lr*64 + kk*4 + lk];
    #pragma unroll
    for (int ct = 0; ct < 4; ++ct){
      const half8v* Bb = (const half8v*)(fc1h + (size_t)(colbase + ct*16 + lr)*512);
      half8v b = Bb[kk*4 + lk];
      acc[ct] = __builtin_amdgcn_mfma_f32_16x16x32_f16(a, b, acc[ct], 0, 0, 0);
    }
    if (doL){
      half8v b = *(const half8v*)(fcwh + (size_t)lr*512 + kk*32 + lk*8);
      accL = __builtin_amdgcn_mfma_f32_16x16x32_f16(a, b, accL, 0, 0, 0);
    }
  }

  float cf[4];
  #pragma unroll
  for (int r = 0; r < 4; ++r)
    cf[r] = (float)cntt[p*NG + rowbase + lk*4 + r];
  #pragma unroll
  for (int ct = 0; ct < 4; ++ct){
    int col = colbase + ct*16 + lr;
    float bv = fc1_b[col];
    float sv = 0.f;
    #pragma unroll
    for (int r = 0; r < 4; ++r)
      sv += cf[r] * tanhf(acc[ct][r] + bv);
    sv += __shfl_xor(sv, 16);
    sv += __shfl_xor(sv, 32);
    if (l < 16) atomicAdd(&acc_p[p*128 + col], sv);
  }
  if (doL){
    #pragma unroll
    for (int r = 0; r < 4; ++r)
      Lb[((size_t)p*NG + rowbase + lk*4 + r)*16 + lr] = accL[r];
  }
}

// ---- hagg write + logits gather; beta recomputed per-block (acc is tiny/L2) ----
__global__ void k_final(const __half* __restrict__ ft0, const __half* __restrict__ ft1,
                        const int* __restrict__ tgt0, const int* __restrict__ tgt1,
                        const float* __restrict__ acc, const float* __restrict__ fc2_w,
                        const float* __restrict__ Lb, const float* __restrict__ fc_b,
                        float* __restrict__ d_out){
  __shared__ float bsh[2];
  int b = blockIdx.x, t = threadIdx.x;  // 512 threads
  if (t < 64){
    float s0 = acc[t]*fc2_w[t] + acc[t+64]*fc2_w[t+64];
    float s1 = acc[128+t]*fc2_w[t] + acc[192+t]*fc2_w[t+64];
    #pragma unroll
    for (int mask = 1; mask < 64; mask <<= 1){
      s0 += __shfl_xor(s0, mask, 64);
      s1 += __shfl_xor(s1, mask, 64);
    }
    if (t == 0){
      float z0 = s0 / (float)NB, z1 = s1 / (float)NB;
      float mz = fmaxf(z0, z1);
      float e0 = expf(z0 - mz), e1 = expf(z1 - mz);
      float inv = 1.f / (e0 + e1);
      bsh[0] = e0*inv; bsh[1] = e1*inv;
    }
  }
  __syncthreads();
  float b0 = bsh[0], b1 = bsh[1];
  int g0 = tgt0[b], g1 = tgt1[b];
  float v0 = __half2float(ft0[(size_t)g0*512 + t]);
  float v1 = __half2float(ft1[(size_t)g1*512 + t]);
  d_out[(size_t)NB*OUTD + (size_t)b*512 + t] = b0*v0 + b1*v1;
  if (t < OUTD){
    float lv = b0*Lb[(size_t)g0*16 + t] + b1*Lb[((size_t)NG + g1)*16 + t] + fc_b[t];
    d_out[(size_t)b*OUTD + t] = lv;
  }
}

extern "C" void kernel_launch(void* const* d_in, const int* in_sizes, int n_in,
                              void* d_out, int out_size, void* d_ws, size_t ws_size,
                              hipStream_t stream){
  const float* feat0  = (const float*)d_in[0];
  const float* feat1  = (const float*)d_in[1];
  const float* W0     = (const float*)d_in[2];
  const float* b0     = (const float*)d_in[3];
  const float* W1     = (const float*)d_in[4];
  const float* b1     = (const float*)d_in[5];
  const float* r_vec  = (const float*)d_in[6];
  const float* attn0  = (const float*)d_in[7];
  const float* attn1  = (const float*)d_in[8];
  const float* fc1_w  = (const float*)d_in[9];
  const float* fc1_b  = (const float*)d_in[10];
  const float* fc2_w  = (const float*)d_in[11];
  const float* fc_w   = (const float*)d_in[12];
  const float* fc_b   = (const float*)d_in[13];
  const int*   idx0   = (const int*)d_in[14];
  const int*   idx1   = (const int*)d_in[15];
  const int*   mpi0   = (const int*)d_in[16];
  const int*   mdst0  = (const int*)d_in[17];
  const int*   mtgt0  = (const int*)d_in[18];
  const int*   mpi1   = (const int*)d_in[19];
  const int*   mdst1  = (const int*)d_in[20];
  const int*   mtgt1  = (const int*)d_in[21];

  float* ws      = (float*)d_ws;
  __half* tf16   = (__half*)(ws + OFF_TF16);
  float* finals  = ws + OFF_FINALS;
  float* acc     = ws + OFF_ACC;
  __half* wc0    = (__half*)(ws + OFF_WC0);
  __half* wc1    = (__half*)(ws + OFF_WC1);
  float* bc0     = ws + OFF_BC0;
  float* bc1     = ws + OFF_BC1;
  __half* fc1h   = (__half*)(ws + OFF_FC1H);
  __half* P      = (__half*)(ws + OFF_P);
  int4*  sorted  = (int4*)(ws + OFF_SORTED);
  int*   counts  = (int*)(ws + OFF_COUNTS);
  int*   cntt    = (int*)(ws + OFF_CNTT);
  int*   curs    = (int*)(ws + OFF_CURS);
  int*   offs    = (int*)(ws + OFF_OFFS);
  __half* ft16o  = (__half*)(ws + OFF_FT16);
  __half* ft0h   = ft16o;
  __half* ft1h   = ft16o + (size_t)NG*512;
  float* Lb      = ws + OFF_L;
  __half* fcwh   = (__half*)(ws + OFF_FCWH);

  k_wcat<<<298, 128, 0, stream>>>(r_vec, attn0, attn1, W0, b0, W1, b1,
                                  fc1_w, fc_w, wc0, bc0, wc1, bc1, fc1h, fcwh,
                                  counts, finals, acc);
  k_hist3<<<(2*NE + 2*NB + 255)/256, 256, 0, stream>>>(mdst0, mdst1, mtgt0, mtgt1,
                                                       counts, cntt);
  k_scan<<<1, 1024, 0, stream>>>(counts, offs, curs);
  k_mid<<<NB_TF + NB_SC, 256, 0, stream>>>(feat0, idx0, feat1, idx1,
                                           wc0, bc0, wc1, bc1,
                                           mpi0, mdst0, mpi1, mdst1,
                                           offs, curs, sorted, tf16, P);
  k_seg<<<NG, 128, 0, stream>>>(tf16, P, sorted, offs, finals, ft16o);
  k_s1g<<<512, 256, 0, stream>>>(ft16o, cntt, fc1h, fc1_b, fcwh, Lb, acc);
  k_final<<<NB, 512, 0, stream>>>(ft0h, ft1h, mtgt0, mtgt1, acc, fc2_w, Lb, fc_b,
                                  (float*)d_out);
}